// Round 15
// baseline (11276.098 us; speedup 1.0000x reference)
//
#include <hip/hip_runtime.h>
#include <cmath>

#define L_ 512
#define B_ 128
#define D_ 1024
#define H_ 1024
#define PKN (B_ * H_)  // one packed-h buffer: 128K dwords = 512 KB

typedef __attribute__((ext_vector_type(8))) short bf16x8;
typedef __attribute__((ext_vector_type(4))) float f32x4;
typedef __attribute__((ext_vector_type(4))) unsigned uint4v;

static __device__ __forceinline__ unsigned short f32_bf16_rn(float f) {
  unsigned u = __float_as_uint(f);
  u += 0x7FFFu + ((u >> 16) & 1u);
  return (unsigned short)(u >> 16);
}
static __device__ __forceinline__ float bf16_f32(unsigned short h) {
  return __uint_as_float(((unsigned)h) << 16);
}

static __device__ __forceinline__ void pack8(const float4& u, const float4& v,
                                             bf16x8& hi, bf16x8& lo) {
  float f[8] = {u.x, u.y, u.z, u.w, v.x, v.y, v.z, v.w};
#pragma unroll
  for (int i = 0; i < 8; ++i) {
    const unsigned short h = f32_bf16_rn(f[i]);
    hi[i] = (short)h;
    lo[i] = (short)f32_bf16_rn(f[i] - bf16_f32(h));
  }
}

// ---------------------------------------------------------------------------
// Kernel A: xi = x @ Wi^T + bi, split-bf16 3-MFMA. (unchanged — R7-proven)
// ---------------------------------------------------------------------------
__global__ __launch_bounds__(256) void xi_gemm_mfma(
    const float* __restrict__ x, const float* __restrict__ Wi,
    const float* __restrict__ bi, float* __restrict__ out) {
  __shared__ unsigned short Ahi[128 * 32], Alo[128 * 32];
  __shared__ unsigned short Bhi[128 * 32], Blo[128 * 32];
  const int tid = threadIdx.x;
  const int bm = blockIdx.x, bn = blockIdx.y;
  const int lane = tid & 63, wv = tid >> 6;
  const int wm = wv >> 1, wn = wv & 1;

  const float* Ag = x + (size_t)bm * 128 * D_;
  const float* Bg = Wi + (size_t)bn * 128 * D_;

  f32x4 acc[4][4];
#pragma unroll
  for (int mi = 0; mi < 4; ++mi)
#pragma unroll
    for (int nj = 0; nj < 4; ++nj) acc[mi][nj] = (f32x4){0.f, 0.f, 0.f, 0.f};

  const int r = tid >> 1;
  const int h2 = tid & 1;
  const int sw = r & 3;
  const int s0 = (h2 * 2) ^ sw, s1 = (h2 * 2 + 1) ^ sw;
  const int fr = lane & 15, kg = lane >> 4;

  for (int k0 = 0; k0 < D_; k0 += 32) {
    __syncthreads();
    {
      const float* pa = &Ag[(size_t)r * D_ + k0 + h2 * 16];
      const float* pb = &Bg[(size_t)r * D_ + k0 + h2 * 16];
      const float4 a0 = *(const float4*)(pa + 0), a1 = *(const float4*)(pa + 4);
      const float4 a2 = *(const float4*)(pa + 8), a3 = *(const float4*)(pa + 12);
      const float4 b0 = *(const float4*)(pb + 0), b1 = *(const float4*)(pb + 4);
      const float4 b2 = *(const float4*)(pb + 8), b3 = *(const float4*)(pb + 12);
      bf16x8 h, l;
      pack8(a0, a1, h, l);
      *(bf16x8*)&Ahi[r * 32 + s0 * 8] = h;
      *(bf16x8*)&Alo[r * 32 + s0 * 8] = l;
      pack8(a2, a3, h, l);
      *(bf16x8*)&Ahi[r * 32 + s1 * 8] = h;
      *(bf16x8*)&Alo[r * 32 + s1 * 8] = l;
      pack8(b0, b1, h, l);
      *(bf16x8*)&Bhi[r * 32 + s0 * 8] = h;
      *(bf16x8*)&Blo[r * 32 + s0 * 8] = l;
      pack8(b2, b3, h, l);
      *(bf16x8*)&Bhi[r * 32 + s1 * 8] = h;
      *(bf16x8*)&Blo[r * 32 + s1 * 8] = l;
    }
    __syncthreads();

    bf16x8 Ah[4], Al[4], Bh[4], Bl[4];
#pragma unroll
    for (int mi = 0; mi < 4; ++mi) {
      const int row = wm * 64 + mi * 16 + fr;
      const int sl = kg ^ (row & 3);
      Ah[mi] = *(const bf16x8*)&Ahi[row * 32 + sl * 8];
      Al[mi] = *(const bf16x8*)&Alo[row * 32 + sl * 8];
    }
#pragma unroll
    for (int nj = 0; nj < 4; ++nj) {
      const int row = wn * 64 + nj * 16 + fr;
      const int sl = kg ^ (row & 3);
      Bh[nj] = *(const bf16x8*)&Bhi[row * 32 + sl * 8];
      Bl[nj] = *(const bf16x8*)&Blo[row * 32 + sl * 8];
    }
#pragma unroll
    for (int mi = 0; mi < 4; ++mi)
#pragma unroll
      for (int nj = 0; nj < 4; ++nj) {
        acc[mi][nj] = __builtin_amdgcn_mfma_f32_16x16x32_bf16(
            Ah[mi], Bh[nj], acc[mi][nj], 0, 0, 0);
        acc[mi][nj] = __builtin_amdgcn_mfma_f32_16x16x32_bf16(
            Ah[mi], Bl[nj], acc[mi][nj], 0, 0, 0);
        acc[mi][nj] = __builtin_amdgcn_mfma_f32_16x16x32_bf16(
            Al[mi], Bh[nj], acc[mi][nj], 0, 0, 0);
      }
  }

  const int fq = lane >> 4;
#pragma unroll
  for (int nj = 0; nj < 4; ++nj) {
    const int col = bn * 128 + wn * 64 + nj * 16 + fr;
    const float bias = bi[col];
#pragma unroll
    for (int mi = 0; mi < 4; ++mi)
#pragma unroll
      for (int reg = 0; reg < 4; ++reg) {
        const size_t row = (size_t)bm * 128 + wm * 64 + mi * 16 + fq * 4 + reg;
        out[row * H_ + col] = acc[mi][nj][reg] + bias;
      }
  }
}

// ---------------------------------------------------------------------------
// Kernel B v15: h_t = tanh(xi_t + h_{t-1} @ Wh^T + bh)
//
// FULLY WAVE-DECOUPLED scan. R14 post-mortem: VALU cut 4x, time unchanged
// -> critical path = serial exchange latency + intra-block coupling (3
// syncthreads + LDS reduce per step). v15 removes ALL of it:
//
//  * 128 blocks (8 groups x 16), 64 j-rows/block. Wave wv owns the COMPLETE
//    16j x 16b tile (j0 = c*64 + wv*16) with FULL K=1024: 32 kt x 3 MFMA
//    as 3 independent acc chains. No K-split -> no LDS reduce, no finisher,
//    ZERO __syncthreads in the step loop.
//  * Per-wave flags: flag[g][c*4+wv] = t+1 after own vmcnt(0) drain. Poll:
//    each lane one flag (64/group), __all(f >= t). Waves never wait on
//    siblings. Generation safety: entering step t requires all flags >= t
//    => all gen-(t-2) reads done before pk[t&1] overwrite (ping-pong OK).
//  * Wh-hi: 64 rows = 128 KB LDS (XOR-swizzled, read-only after init).
//    Wh-lo: full-K row per lane in REGISTERS (32 x bf16x8 = 128 VGPR;
//    1 wave/SIMD affords it — watch VGPR_Count for spill).
//  * Producer-packed pk exchange + v_perm unpack (R14-verified), xi float4
//    register-carry, sc1 store/load primitives (R2-lineage) all unchanged.
// ---------------------------------------------------------------------------
__global__ __launch_bounds__(256, 1) void rnn_scan(
    const float* __restrict__ h0, const float* __restrict__ Wh,
    const float* __restrict__ bh, float* __restrict__ out,
    unsigned int* __restrict__ flags, unsigned int* __restrict__ pk) {
  __shared__ unsigned short WhHi[64 * 1024];  // 128 KB
  const int tid = threadIdx.x;
  const int g = blockIdx.x & 7;
  const int c = blockIdx.x >> 3;   // 0..15
  const int j0b = c << 6;          // block's 64 j-rows
  const int b0 = g << 4;

  // ---- Stage Wh-hi rows j0b..j0b+63 into LDS (once) ----
#pragma unroll
  for (int i = 0; i < 32; ++i) {
    const int sid = i * 256 + tid;      // 8192 slots of 8 floats
    const int jr = sid >> 7;            // 0..63
    const int s = sid & 127;            // k-slot
    const float* p = &Wh[(size_t)(j0b + jr) * H_ + s * 8];
    const float4 u = *(const float4*)(p);
    const float4 v4 = *(const float4*)(p + 4);
    bf16x8 hi, lo;
    pack8(u, v4, hi, lo);
    *(bf16x8*)&WhHi[jr * 1024 + (s ^ (jr & 7)) * 8] = hi;
  }

  const int lane = tid & 63;
  const int wv = tid >> 6;
  const int fr = lane & 15;        // A-row (j in tile) == B-col (batch)
  const int kb = lane >> 4;        // k-sub-block (8 elements)
  const int fq = lane >> 4;        // D row-quad
  const int jw = (wv << 4) + fr;   // LDS row of my A fragment
  const int frx7 = fr & 7;
  const int jwt = jw * 1024;

  // ---- Wh-lo full-K row -> registers (32 x bf16x8) ----
  bf16x8 wlo[32];
  {
    const float* wrow = Wh + (size_t)(j0b + jw) * H_;
#pragma unroll
    for (int kt = 0; kt < 32; ++kt) {
      const float* p = wrow + kt * 32 + kb * 8;
      const float4 u = *(const float4*)(p);
      const float4 v4 = *(const float4*)(p + 4);
      bf16x8 hi;
      pack8(u, v4, hi, wlo[kt]);
    }
  }

  // Output mapping: lane holds j = j0w + fq*4 + reg (4 consecutive), b = b0+fr
  const int j0w = j0b + (wv << 4);
  const int jo = j0w + (fq << 2);
  const int bo = b0 + fr;
  const float4 bias4 = *(const float4*)&bh[jo];
  unsigned int* gflags = flags + (g << 6);
  const int myflag = (c << 2) + wv;
  __syncthreads();  // WhHi ready — the ONLY barrier in this kernel

  const size_t obase = (size_t)bo * H_ + jo;   // element offset of my float4
  float4 xi4 = *(const float4*)&out[obase];    // xi[t=0] (exclusively ours)
  for (int t = 0; t < L_; ++t) {
    // ---- wait for gen-(t-1): all 64 wave-flags of my group >= t ----
    if (t > 0) {
      const unsigned tgt = (unsigned)t;
      int spins = 0;
      while (true) {
        const unsigned f = __hip_atomic_load(&gflags[lane], __ATOMIC_RELAXED,
                                             __HIP_MEMORY_SCOPE_AGENT);
        if (__all((int)(f >= tgt))) break;
        if (++spins > 16) __builtin_amdgcn_s_sleep(1);
      }
    }

    f32x4 a1 = (f32x4){0.f, 0.f, 0.f, 0.f};
    f32x4 a2 = (f32x4){0.f, 0.f, 0.f, 0.f};
    f32x4 a3 = (f32x4){0.f, 0.f, 0.f, 0.f};
    if (t == 0) {
      // h0 f32 path (input, immutable -> plain loads) + consumer pack
      const float* hb = h0 + (size_t)(b0 + fr) * H_ + kb * 8;
#pragma unroll
      for (int kt = 0; kt < 32; ++kt) {
        const float4 u = *(const float4*)(hb + kt * 32);
        const float4 v4 = *(const float4*)(hb + kt * 32 + 4);
        bf16x8 Bh, Bl;
        pack8(u, v4, Bh, Bl);
        const int ps = ((kt << 2) + kb) ^ frx7;
        const bf16x8 Ah = *(const bf16x8*)&WhHi[jwt + ps * 8];
        a1 = __builtin_amdgcn_mfma_f32_16x16x32_bf16(Ah, Bh, a1, 0, 0, 0);
        a2 = __builtin_amdgcn_mfma_f32_16x16x32_bf16(Ah, Bl, a2, 0, 0, 0);
        a3 = __builtin_amdgcn_mfma_f32_16x16x32_bf16(wlo[kt], Bh, a3, 0, 0, 0);
      }
    } else {
      // packed path: 4 x u64 bypass loads + v_perm unpack per kt
      const unsigned long long* pk64 = (const unsigned long long*)(
          pk + (size_t)((t + 1) & 1) * PKN) +
          (((size_t)(b0 + fr) * H_ + kb * 8) >> 1);
#pragma unroll
      for (int kt = 0; kt < 32; ++kt) {
        const unsigned long long q0 = __hip_atomic_load(
            &pk64[kt * 16 + 0], __ATOMIC_RELAXED, __HIP_MEMORY_SCOPE_AGENT);
        const unsigned long long q1 = __hip_atomic_load(
            &pk64[kt * 16 + 1], __ATOMIC_RELAXED, __HIP_MEMORY_SCOPE_AGENT);
        const unsigned long long q2 = __hip_atomic_load(
            &pk64[kt * 16 + 2], __ATOMIC_RELAXED, __HIP_MEMORY_SCOPE_AGENT);
        const unsigned long long q3 = __hip_atomic_load(
            &pk64[kt * 16 + 3], __ATOMIC_RELAXED, __HIP_MEMORY_SCOPE_AGENT);
        const unsigned u0 = (unsigned)q0, u1 = (unsigned)(q0 >> 32);
        const unsigned u2 = (unsigned)q1, u3 = (unsigned)(q1 >> 32);
        const unsigned u4 = (unsigned)q2, u5 = (unsigned)(q2 >> 32);
        const unsigned u6 = (unsigned)q3, u7 = (unsigned)(q3 >> 32);
        union { uint4v u; bf16x8 v; } ch, cl;
        ch.u.x = __builtin_amdgcn_perm(u1, u0, 0x07060302u);
        ch.u.y = __builtin_amdgcn_perm(u3, u2, 0x07060302u);
        ch.u.z = __builtin_amdgcn_perm(u5, u4, 0x07060302u);
        ch.u.w = __builtin_amdgcn_perm(u7, u6, 0x07060302u);
        cl.u.x = __builtin_amdgcn_perm(u1, u0, 0x05040100u);
        cl.u.y = __builtin_amdgcn_perm(u3, u2, 0x05040100u);
        cl.u.z = __builtin_amdgcn_perm(u5, u4, 0x05040100u);
        cl.u.w = __builtin_amdgcn_perm(u7, u6, 0x05040100u);
        const int ps = ((kt << 2) + kb) ^ frx7;
        const bf16x8 Ah = *(const bf16x8*)&WhHi[jwt + ps * 8];
        a1 = __builtin_amdgcn_mfma_f32_16x16x32_bf16(Ah, ch.v, a1, 0, 0, 0);
        a2 = __builtin_amdgcn_mfma_f32_16x16x32_bf16(Ah, cl.v, a2, 0, 0, 0);
        a3 = __builtin_amdgcn_mfma_f32_16x16x32_bf16(wlo[kt], ch.v, a3, 0, 0, 0);
      }
    }
    const size_t tB = (size_t)t * B_ * H_;
    // xi[t+1] prefetch (plain cached; exclusively ours; register carry)
    const size_t nB = tB + (size_t)(t + 1 < L_ ? B_ * H_ : 0);
    const float4 xin4 = *(const float4*)&out[nB + obase];

    // ---- finish in-lane: D = a1+a2+a3, tanh, pack, store ----
    float v[4];
    unsigned pkw[4];
#pragma unroll
    for (int rgi = 0; rgi < 4; ++rgi) {
      const float s = a1[rgi] + a2[rgi] + a3[rgi] +
                      ((const float*)&xi4)[rgi] + ((const float*)&bias4)[rgi];
      v[rgi] = tanhf(s);
      const unsigned short hp = f32_bf16_rn(v[rgi]);
      const unsigned short lp = f32_bf16_rn(v[rgi] - bf16_f32(hp));
      pkw[rgi] = ((unsigned)hp << 16) | lp;
    }
    {
      // out: 2 x u64 sc1 stores (write-through to coherence point)
      unsigned long long o0, o1, p0, p1;
      __builtin_memcpy(&o0, &v[0], 8);
      __builtin_memcpy(&o1, &v[2], 8);
      __builtin_memcpy(&p0, &pkw[0], 8);
      __builtin_memcpy(&p1, &pkw[2], 8);
      unsigned long long* outp = (unsigned long long*)&out[tB + obase];
      __hip_atomic_store(&outp[0], o0, __ATOMIC_RELAXED, __HIP_MEMORY_SCOPE_AGENT);
      __hip_atomic_store(&outp[1], o1, __ATOMIC_RELAXED, __HIP_MEMORY_SCOPE_AGENT);
      unsigned long long* pkp = (unsigned long long*)(
          pk + (size_t)(t & 1) * PKN + obase);
      __hip_atomic_store(&pkp[0], p0, __ATOMIC_RELAXED, __HIP_MEMORY_SCOPE_AGENT);
      __hip_atomic_store(&pkp[1], p1, __ATOMIC_RELAXED, __HIP_MEMORY_SCOPE_AGENT);
    }

    if (t + 1 < L_) {
      // ---- per-wave release: drain MY stores, publish MY flag ----
      asm volatile("s_waitcnt vmcnt(0)" ::: "memory");
      if (lane == 0)
        __hip_atomic_store(&gflags[myflag], (unsigned)(t + 1),
                           __ATOMIC_RELAXED, __HIP_MEMORY_SCOPE_AGENT);
    }
    xi4 = xin4;
  }
}

// ---------------------------------------------------------------------------
extern "C" void kernel_launch(void* const* d_in, const int* in_sizes, int n_in,
                              void* d_out, int out_size, void* d_ws, size_t ws_size,
                              hipStream_t stream) {
  const float* x    = (const float*)d_in[0];
  const float* h0   = (const float*)d_in[1];
  const float* Wi_w = (const float*)d_in[2];
  const float* Wi_b = (const float*)d_in[3];
  const float* Wh_w = (const float*)d_in[4];
  const float* Wh_b = (const float*)d_in[5];
  float* out = (float*)d_out;
  unsigned int* flags = (unsigned int*)d_ws;                 // 4 KB
  unsigned int* pk = (unsigned int*)((char*)d_ws + 4096);    // 2 x 512 KB

  // Phase 1: xi -> d_out (split-bf16 MFMA)
  hipLaunchKernelGGL(xi_gemm_mfma, dim3(512, 8), dim3(256), 0, stream,
                     x, Wi_w, Wi_b, out);

  // Zero the flags (graph replays reuse d_ws; flags must start 0)
  hipMemsetAsync(d_ws, 0, 4096, stream);

  // Phase 2: cooperative scan — 128 blocks (8 groups x 16), wave-decoupled
  void* args[] = { (void*)&h0, (void*)&Wh_w, (void*)&Wh_b, (void*)&out,
                   (void*)&flags, (void*)&pk };
  hipLaunchCooperativeKernel((void*)rnn_scan, dim3(128), dim3(256), args, 0, stream);
}

// Round 16
// 6925.095 us; speedup vs baseline: 1.6283x; 1.6283x over previous
//
#include <hip/hip_runtime.h>
#include <cmath>

#define L_ 512
#define B_ 128
#define D_ 1024
#define H_ 1024
#define PKN (B_ * H_)  // one packed-h buffer: 128K dwords = 512 KB

typedef __attribute__((ext_vector_type(8))) short bf16x8;
typedef __attribute__((ext_vector_type(4))) float f32x4;
typedef __attribute__((ext_vector_type(4))) unsigned uint4v;

static __device__ __forceinline__ unsigned short f32_bf16_rn(float f) {
  unsigned u = __float_as_uint(f);
  u += 0x7FFFu + ((u >> 16) & 1u);
  return (unsigned short)(u >> 16);
}
static __device__ __forceinline__ float bf16_f32(unsigned short h) {
  return __uint_as_float(((unsigned)h) << 16);
}

static __device__ __forceinline__ void pack8(const float4& u, const float4& v,
                                             bf16x8& hi, bf16x8& lo) {
  float f[8] = {u.x, u.y, u.z, u.w, v.x, v.y, v.z, v.w};
#pragma unroll
  for (int i = 0; i < 8; ++i) {
    const unsigned short h = f32_bf16_rn(f[i]);
    hi[i] = (short)h;
    lo[i] = (short)f32_bf16_rn(f[i] - bf16_f32(h));
  }
}

// ---------------------------------------------------------------------------
// Kernel A: xi = x @ Wi^T + bi, split-bf16 3-MFMA. (unchanged — R7-proven)
// ---------------------------------------------------------------------------
__global__ __launch_bounds__(256) void xi_gemm_mfma(
    const float* __restrict__ x, const float* __restrict__ Wi,
    const float* __restrict__ bi, float* __restrict__ out) {
  __shared__ unsigned short Ahi[128 * 32], Alo[128 * 32];
  __shared__ unsigned short Bhi[128 * 32], Blo[128 * 32];
  const int tid = threadIdx.x;
  const int bm = blockIdx.x, bn = blockIdx.y;
  const int lane = tid & 63, wv = tid >> 6;
  const int wm = wv >> 1, wn = wv & 1;

  const float* Ag = x + (size_t)bm * 128 * D_;
  const float* Bg = Wi + (size_t)bn * 128 * D_;

  f32x4 acc[4][4];
#pragma unroll
  for (int mi = 0; mi < 4; ++mi)
#pragma unroll
    for (int nj = 0; nj < 4; ++nj) acc[mi][nj] = (f32x4){0.f, 0.f, 0.f, 0.f};

  const int r = tid >> 1;
  const int h2 = tid & 1;
  const int sw = r & 3;
  const int s0 = (h2 * 2) ^ sw, s1 = (h2 * 2 + 1) ^ sw;
  const int fr = lane & 15, kg = lane >> 4;

  for (int k0 = 0; k0 < D_; k0 += 32) {
    __syncthreads();
    {
      const float* pa = &Ag[(size_t)r * D_ + k0 + h2 * 16];
      const float* pb = &Bg[(size_t)r * D_ + k0 + h2 * 16];
      const float4 a0 = *(const float4*)(pa + 0), a1 = *(const float4*)(pa + 4);
      const float4 a2 = *(const float4*)(pa + 8), a3 = *(const float4*)(pa + 12);
      const float4 b0 = *(const float4*)(pb + 0), b1 = *(const float4*)(pb + 4);
      const float4 b2 = *(const float4*)(pb + 8), b3 = *(const float4*)(pb + 12);
      bf16x8 h, l;
      pack8(a0, a1, h, l);
      *(bf16x8*)&Ahi[r * 32 + s0 * 8] = h;
      *(bf16x8*)&Alo[r * 32 + s0 * 8] = l;
      pack8(a2, a3, h, l);
      *(bf16x8*)&Ahi[r * 32 + s1 * 8] = h;
      *(bf16x8*)&Alo[r * 32 + s1 * 8] = l;
      pack8(b0, b1, h, l);
      *(bf16x8*)&Bhi[r * 32 + s0 * 8] = h;
      *(bf16x8*)&Blo[r * 32 + s0 * 8] = l;
      pack8(b2, b3, h, l);
      *(bf16x8*)&Bhi[r * 32 + s1 * 8] = h;
      *(bf16x8*)&Blo[r * 32 + s1 * 8] = l;
    }
    __syncthreads();

    bf16x8 Ah[4], Al[4], Bh[4], Bl[4];
#pragma unroll
    for (int mi = 0; mi < 4; ++mi) {
      const int row = wm * 64 + mi * 16 + fr;
      const int sl = kg ^ (row & 3);
      Ah[mi] = *(const bf16x8*)&Ahi[row * 32 + sl * 8];
      Al[mi] = *(const bf16x8*)&Alo[row * 32 + sl * 8];
    }
#pragma unroll
    for (int nj = 0; nj < 4; ++nj) {
      const int row = wn * 64 + nj * 16 + fr;
      const int sl = kg ^ (row & 3);
      Bh[nj] = *(const bf16x8*)&Bhi[row * 32 + sl * 8];
      Bl[nj] = *(const bf16x8*)&Blo[row * 32 + sl * 8];
    }
#pragma unroll
    for (int mi = 0; mi < 4; ++mi)
#pragma unroll
      for (int nj = 0; nj < 4; ++nj) {
        acc[mi][nj] = __builtin_amdgcn_mfma_f32_16x16x32_bf16(
            Ah[mi], Bh[nj], acc[mi][nj], 0, 0, 0);
        acc[mi][nj] = __builtin_amdgcn_mfma_f32_16x16x32_bf16(
            Ah[mi], Bl[nj], acc[mi][nj], 0, 0, 0);
        acc[mi][nj] = __builtin_amdgcn_mfma_f32_16x16x32_bf16(
            Al[mi], Bh[nj], acc[mi][nj], 0, 0, 0);
      }
  }

  const int fq = lane >> 4;
#pragma unroll
  for (int nj = 0; nj < 4; ++nj) {
    const int col = bn * 128 + wn * 64 + nj * 16 + fr;
    const float bias = bi[col];
#pragma unroll
    for (int mi = 0; mi < 4; ++mi)
#pragma unroll
      for (int reg = 0; reg < 4; ++reg) {
        const size_t row = (size_t)bm * 128 + wm * 64 + mi * 16 + fq * 4 + reg;
        out[row * H_ + col] = acc[mi][nj][reg] + bias;
      }
  }
}

// ---------------------------------------------------------------------------
// Kernel B v16: h_t = tanh(xi_t + h_{t-1} @ Wh^T + bh)
//
// R14 compute structure (256 blocks @1/CU, 8 groups x 32 blocks of 32 j,
// 2-way K-split + LDS reduce, Wh-hi LDS / Wh-lo regs, producer-packed pk
// exchange with v_perm unpack). Four surgical critical-path changes:
//
//  1. xi prefetch issued BEFORE the k-loop: its ~1us HBM miss (0.5 MB/step
//     = the whole FETCH_SIZE) was sitting inside the pre-publish vmcnt(0)
//     drain, on the serial chain, every step.
//  2. out stores are PLAIN cached (write-back): nobody reads out[t] but our
//     own block (h-exchange is via pk). Drain now acks pk at MALL only.
//  3. PER-WAVE release flags (protocol validated by v15): each wave drains
//     its own stores (vmcnt 0) and publishes flags[g*128 + c*4 + wv] = t+1.
//     Consumers poll 128 flags as 64 u64 pairs (one per lane), per wave,
//     no __syncthreads around release/poll. Only the reduce barrier remains.
//     Ping-pong safety: entering step t requires all flags >= t => every
//     wave finished step t-1 INCLUDING its pk[t&1] reads (publish follows
//     vmcnt(0) which drains loads) => overwriting pk[t&1] at t is safe.
//  4. Hot-spin 32 polls before s_sleep.
// ---------------------------------------------------------------------------
__global__ __launch_bounds__(256, 1) void rnn_scan(
    const float* __restrict__ h0, const float* __restrict__ Wh,
    const float* __restrict__ bh, float* __restrict__ out,
    unsigned int* __restrict__ flags, unsigned int* __restrict__ pk) {
  __shared__ unsigned short WhHi[32 * 1024];  // 64 KB
  __shared__ float red[2 * 32 * 17];
  const int tid = threadIdx.x;
  const int g = blockIdx.x & 7;
  const int c = blockIdx.x >> 3;
  const int j0 = c << 5;
  const int b0 = g << 4;

  // ---- Stage Wh-hi rows j0..j0+31 into LDS (once) ----
#pragma unroll
  for (int i = 0; i < 16; ++i) {
    const int sid = i * 256 + tid;
    const int jr = sid >> 7;
    const int s = sid & 127;
    const float* p = &Wh[(size_t)(j0 + jr) * H_ + s * 8];
    const float4 u = *(const float4*)(p);
    const float4 v4 = *(const float4*)(p + 4);
    bf16x8 hi, lo;
    pack8(u, v4, hi, lo);
    *(bf16x8*)&WhHi[jr * 1024 + (s ^ (jr & 7)) * 8] = hi;
  }

  const int lane = tid & 63;
  const int wv = tid >> 6;
  const int jh = wv >> 1;
  const int kh = wv & 1;
  const int fr = lane & 15;
  const int kb = lane >> 4;
  const int frx7 = fr & 7;
  const int jrt = (jh * 16 + fr) * 1024;

  // ---- Wh-lo -> registers: 16 k-tiles x 8 bf16 per lane ----
  bf16x8 wlo[16];
  {
    const float* wrow = Wh + (size_t)(j0 + jh * 16 + fr) * H_ + kh * 512;
#pragma unroll
    for (int kt = 0; kt < 16; ++kt) {
      const float* p = wrow + kt * 32 + kb * 8;
      const float4 u = *(const float4*)(p);
      const float4 v4 = *(const float4*)(p + 4);
      bf16x8 hi;
      pack8(u, v4, hi, wlo[kt]);
    }
  }

  const int jf = tid & 31;
  const int bfh = tid >> 5;
  const float bias = bh[j0 + jf];
  unsigned int* gflags = flags + (g << 7);                 // 128 flags/group
  const unsigned long long* fpairs = (const unsigned long long*)gflags;
  const int myflag = (c << 2) | wv;
  __syncthreads();

  const size_t hoffF = (size_t)fr * H_ + kh * 512;
  const size_t obase0 = (size_t)(b0 + bfh) * H_ + (j0 + jf);
  const size_t obase1 = obase0 + (size_t)8 * H_;
  float xi0 = out[obase0];
  float xi1 = out[obase1];
  for (int t = 0; t < L_; ++t) {
    // ---- per-wave wait: all 128 group flags >= t (64 u64 pairs, 1/lane) ----
    if (t > 0) {
      const unsigned tgt = (unsigned)t;
      int spins = 0;
      while (true) {
        const unsigned long long fp = __hip_atomic_load(
            &fpairs[lane], __ATOMIC_RELAXED, __HIP_MEMORY_SCOPE_AGENT);
        if (__all((int)(((unsigned)fp >= tgt) &
                        ((unsigned)(fp >> 32) >= tgt)))) break;
        if (++spins > 32) __builtin_amdgcn_s_sleep(1);
      }
    }
    const size_t tB = (size_t)t * B_ * H_;
    const size_t nB = tB + (size_t)(t + 1 < L_ ? B_ * H_ : 0);
    // xi[t+1] prefetch EARLY — completes under the k-loop, off the drain.
    const float xin0 = out[nB + obase0];
    const float xin1 = out[nB + obase1];

    f32x4 acc = (f32x4){0.f, 0.f, 0.f, 0.f};
    if (t == 0) {
      const unsigned long long* h64 =
          (const unsigned long long*)(h0 + (size_t)b0 * H_);
      const size_t hoff64 = (hoffF >> 1) + kb * 4;
#pragma unroll
      for (int kt = 0; kt < 16; ++kt) {
        const size_t k64 = hoff64 + kt * 16;
        const unsigned long long p0 = __hip_atomic_load(
            &h64[k64 + 0], __ATOMIC_RELAXED, __HIP_MEMORY_SCOPE_AGENT);
        const unsigned long long p1 = __hip_atomic_load(
            &h64[k64 + 1], __ATOMIC_RELAXED, __HIP_MEMORY_SCOPE_AGENT);
        const unsigned long long p2 = __hip_atomic_load(
            &h64[k64 + 2], __ATOMIC_RELAXED, __HIP_MEMORY_SCOPE_AGENT);
        const unsigned long long p3 = __hip_atomic_load(
            &h64[k64 + 3], __ATOMIC_RELAXED, __HIP_MEMORY_SCOPE_AGENT);
        const float4 u = make_float4(__uint_as_float((unsigned)p0),
                                     __uint_as_float((unsigned)(p0 >> 32)),
                                     __uint_as_float((unsigned)p1),
                                     __uint_as_float((unsigned)(p1 >> 32)));
        const float4 v4 = make_float4(__uint_as_float((unsigned)p2),
                                      __uint_as_float((unsigned)(p2 >> 32)),
                                      __uint_as_float((unsigned)p3),
                                      __uint_as_float((unsigned)(p3 >> 32)));
        bf16x8 Bh, Bl;
        pack8(u, v4, Bh, Bl);
        const int ps = (kh * 64 + kt * 4 + kb) ^ frx7;
        const bf16x8 Ah = *(const bf16x8*)&WhHi[jrt + ps * 8];
        acc = __builtin_amdgcn_mfma_f32_16x16x32_bf16(Ah, Bh, acc, 0, 0, 0);
        acc = __builtin_amdgcn_mfma_f32_16x16x32_bf16(Ah, Bl, acc, 0, 0, 0);
        acc = __builtin_amdgcn_mfma_f32_16x16x32_bf16(wlo[kt], Bh, acc, 0, 0, 0);
      }
    } else {
      const unsigned long long* pk64 = (const unsigned long long*)(
          pk + (size_t)((t + 1) & 1) * PKN + (size_t)b0 * H_ + hoffF);
      const size_t pko = (size_t)kb * 4;
#pragma unroll
      for (int kt = 0; kt < 16; ++kt) {
        const size_t k64 = pko + kt * 16;
        const unsigned long long q0 = __hip_atomic_load(
            &pk64[k64 + 0], __ATOMIC_RELAXED, __HIP_MEMORY_SCOPE_AGENT);
        const unsigned long long q1 = __hip_atomic_load(
            &pk64[k64 + 1], __ATOMIC_RELAXED, __HIP_MEMORY_SCOPE_AGENT);
        const unsigned long long q2 = __hip_atomic_load(
            &pk64[k64 + 2], __ATOMIC_RELAXED, __HIP_MEMORY_SCOPE_AGENT);
        const unsigned long long q3 = __hip_atomic_load(
            &pk64[k64 + 3], __ATOMIC_RELAXED, __HIP_MEMORY_SCOPE_AGENT);
        const unsigned u0 = (unsigned)q0, u1 = (unsigned)(q0 >> 32);
        const unsigned u2 = (unsigned)q1, u3 = (unsigned)(q1 >> 32);
        const unsigned u4 = (unsigned)q2, u5 = (unsigned)(q2 >> 32);
        const unsigned u6 = (unsigned)q3, u7 = (unsigned)(q3 >> 32);
        union { uint4v u; bf16x8 v; } ch, cl;
        ch.u.x = __builtin_amdgcn_perm(u1, u0, 0x07060302u);
        ch.u.y = __builtin_amdgcn_perm(u3, u2, 0x07060302u);
        ch.u.z = __builtin_amdgcn_perm(u5, u4, 0x07060302u);
        ch.u.w = __builtin_amdgcn_perm(u7, u6, 0x07060302u);
        cl.u.x = __builtin_amdgcn_perm(u1, u0, 0x05040100u);
        cl.u.y = __builtin_amdgcn_perm(u3, u2, 0x05040100u);
        cl.u.z = __builtin_amdgcn_perm(u5, u4, 0x05040100u);
        cl.u.w = __builtin_amdgcn_perm(u7, u6, 0x05040100u);
        const int ps = (kh * 64 + kt * 4 + kb) ^ frx7;
        const bf16x8 Ah = *(const bf16x8*)&WhHi[jrt + ps * 8];
        acc = __builtin_amdgcn_mfma_f32_16x16x32_bf16(Ah, ch.v, acc, 0, 0, 0);
        acc = __builtin_amdgcn_mfma_f32_16x16x32_bf16(Ah, cl.v, acc, 0, 0, 0);
        acc = __builtin_amdgcn_mfma_f32_16x16x32_bf16(wlo[kt], ch.v, acc, 0, 0, 0);
      }
    }
#pragma unroll
    for (int r4 = 0; r4 < 4; ++r4)
      red[(kh * 32 + jh * 16 + kb * 4 + r4) * 17 + fr] = acc[r4];
    __syncthreads();  // the ONLY block-wide barrier in the loop
    {
      const float s0 = red[(jf) * 17 + bfh] + red[(32 + jf) * 17 + bfh];
      const float s1 = red[(jf) * 17 + bfh + 8] + red[(32 + jf) * 17 + bfh + 8];
      const float v0 = tanhf(s0 + xi0 + bias);
      const float v1 = tanhf(s1 + xi1 + bias);
      // out: PLAIN cached stores (write-back; only our own block reads out)
      out[tB + obase0] = v0;
      out[tB + obase1] = v1;
      // pk: sc1 write-through (the actual exchange payload)
      unsigned int* pkw = pk + (size_t)(t & 1) * PKN;
      const unsigned short h0p = f32_bf16_rn(v0);
      const unsigned short l0p = f32_bf16_rn(v0 - bf16_f32(h0p));
      const unsigned short h1p = f32_bf16_rn(v1);
      const unsigned short l1p = f32_bf16_rn(v1 - bf16_f32(h1p));
      __hip_atomic_store(&pkw[obase0], ((unsigned)h0p << 16) | l0p,
                         __ATOMIC_RELAXED, __HIP_MEMORY_SCOPE_AGENT);
      __hip_atomic_store(&pkw[obase1], ((unsigned)h1p << 16) | l1p,
                         __ATOMIC_RELAXED, __HIP_MEMORY_SCOPE_AGENT);
    }

    if (t + 1 < L_) {
      // ---- per-wave release: drain MY stores, publish MY flag ----
      asm volatile("s_waitcnt vmcnt(0)" ::: "memory");
      if (lane == 0)
        __hip_atomic_store(&gflags[myflag], (unsigned)(t + 1),
                           __ATOMIC_RELAXED, __HIP_MEMORY_SCOPE_AGENT);
    }
    xi0 = xin0;
    xi1 = xin1;
  }
}

// ---------------------------------------------------------------------------
extern "C" void kernel_launch(void* const* d_in, const int* in_sizes, int n_in,
                              void* d_out, int out_size, void* d_ws, size_t ws_size,
                              hipStream_t stream) {
  const float* x    = (const float*)d_in[0];
  const float* h0   = (const float*)d_in[1];
  const float* Wi_w = (const float*)d_in[2];
  const float* Wi_b = (const float*)d_in[3];
  const float* Wh_w = (const float*)d_in[4];
  const float* Wh_b = (const float*)d_in[5];
  float* out = (float*)d_out;
  unsigned int* flags = (unsigned int*)d_ws;                 // 4 KB (8x128)
  unsigned int* pk = (unsigned int*)((char*)d_ws + 4096);    // 2 x 512 KB

  // Phase 1: xi -> d_out (split-bf16 MFMA)
  hipLaunchKernelGGL(xi_gemm_mfma, dim3(512, 8), dim3(256), 0, stream,
                     x, Wi_w, Wi_b, out);

  // Zero the flags (graph replays reuse d_ws; flags must start 0)
  hipMemsetAsync(d_ws, 0, 4096, stream);

  // Phase 2: cooperative scan — 256 blocks (1/CU), per-wave flag sync
  void* args[] = { (void*)&h0, (void*)&Wh_w, (void*)&Wh_b, (void*)&out,
                   (void*)&flags, (void*)&pk };
  hipLaunchCooperativeKernel((void*)rnn_scan, dim3(256), dim3(256), args, 0, stream);
}

// Round 17
// 5421.196 us; speedup vs baseline: 2.0800x; 1.2774x over previous
//
#include <hip/hip_runtime.h>
#include <cmath>

#define L_ 512
#define B_ 128
#define D_ 1024
#define H_ 1024

typedef __attribute__((ext_vector_type(8))) short bf16x8;
typedef __attribute__((ext_vector_type(4))) float f32x4;

static __device__ __forceinline__ unsigned short f32_bf16_rn(float f) {
  unsigned u = __float_as_uint(f);
  u += 0x7FFFu + ((u >> 16) & 1u);
  return (unsigned short)(u >> 16);
}
static __device__ __forceinline__ float bf16_f32(unsigned short h) {
  return __uint_as_float(((unsigned)h) << 16);
}

static __device__ __forceinline__ void pack8(const float4& u, const float4& v,
                                             bf16x8& hi, bf16x8& lo) {
  float f[8] = {u.x, u.y, u.z, u.w, v.x, v.y, v.z, v.w};
#pragma unroll
  for (int i = 0; i < 8; ++i) {
    const unsigned short h = f32_bf16_rn(f[i]);
    hi[i] = (short)h;
    lo[i] = (short)f32_bf16_rn(f[i] - bf16_f32(h));
  }
}

// ---------------------------------------------------------------------------
// Kernel A: xi = x @ Wi^T + bi, split-bf16 3-MFMA. (unchanged — R7-proven)
// ---------------------------------------------------------------------------
__global__ __launch_bounds__(256) void xi_gemm_mfma(
    const float* __restrict__ x, const float* __restrict__ Wi,
    const float* __restrict__ bi, float* __restrict__ out) {
  __shared__ unsigned short Ahi[128 * 32], Alo[128 * 32];
  __shared__ unsigned short Bhi[128 * 32], Blo[128 * 32];
  const int tid = threadIdx.x;
  const int bm = blockIdx.x, bn = blockIdx.y;
  const int lane = tid & 63, wv = tid >> 6;
  const int wm = wv >> 1, wn = wv & 1;

  const float* Ag = x + (size_t)bm * 128 * D_;
  const float* Bg = Wi + (size_t)bn * 128 * D_;

  f32x4 acc[4][4];
#pragma unroll
  for (int mi = 0; mi < 4; ++mi)
#pragma unroll
    for (int nj = 0; nj < 4; ++nj) acc[mi][nj] = (f32x4){0.f, 0.f, 0.f, 0.f};

  const int r = tid >> 1;
  const int h2 = tid & 1;
  const int sw = r & 3;
  const int s0 = (h2 * 2) ^ sw, s1 = (h2 * 2 + 1) ^ sw;
  const int fr = lane & 15, kg = lane >> 4;

  for (int k0 = 0; k0 < D_; k0 += 32) {
    __syncthreads();
    {
      const float* pa = &Ag[(size_t)r * D_ + k0 + h2 * 16];
      const float* pb = &Bg[(size_t)r * D_ + k0 + h2 * 16];
      const float4 a0 = *(const float4*)(pa + 0), a1 = *(const float4*)(pa + 4);
      const float4 a2 = *(const float4*)(pa + 8), a3 = *(const float4*)(pa + 12);
      const float4 b0 = *(const float4*)(pb + 0), b1 = *(const float4*)(pb + 4);
      const float4 b2 = *(const float4*)(pb + 8), b3 = *(const float4*)(pb + 12);
      bf16x8 h, l;
      pack8(a0, a1, h, l);
      *(bf16x8*)&Ahi[r * 32 + s0 * 8] = h;
      *(bf16x8*)&Alo[r * 32 + s0 * 8] = l;
      pack8(a2, a3, h, l);
      *(bf16x8*)&Ahi[r * 32 + s1 * 8] = h;
      *(bf16x8*)&Alo[r * 32 + s1 * 8] = l;
      pack8(b0, b1, h, l);
      *(bf16x8*)&Bhi[r * 32 + s0 * 8] = h;
      *(bf16x8*)&Blo[r * 32 + s0 * 8] = l;
      pack8(b2, b3, h, l);
      *(bf16x8*)&Bhi[r * 32 + s1 * 8] = h;
      *(bf16x8*)&Blo[r * 32 + s1 * 8] = l;
    }
    __syncthreads();

    bf16x8 Ah[4], Al[4], Bh[4], Bl[4];
#pragma unroll
    for (int mi = 0; mi < 4; ++mi) {
      const int row = wm * 64 + mi * 16 + fr;
      const int sl = kg ^ (row & 3);
      Ah[mi] = *(const bf16x8*)&Ahi[row * 32 + sl * 8];
      Al[mi] = *(const bf16x8*)&Alo[row * 32 + sl * 8];
    }
#pragma unroll
    for (int nj = 0; nj < 4; ++nj) {
      const int row = wn * 64 + nj * 16 + fr;
      const int sl = kg ^ (row & 3);
      Bh[nj] = *(const bf16x8*)&Bhi[row * 32 + sl * 8];
      Bl[nj] = *(const bf16x8*)&Blo[row * 32 + sl * 8];
    }
#pragma unroll
    for (int mi = 0; mi < 4; ++mi)
#pragma unroll
      for (int nj = 0; nj < 4; ++nj) {
        acc[mi][nj] = __builtin_amdgcn_mfma_f32_16x16x32_bf16(
            Ah[mi], Bh[nj], acc[mi][nj], 0, 0, 0);
        acc[mi][nj] = __builtin_amdgcn_mfma_f32_16x16x32_bf16(
            Ah[mi], Bl[nj], acc[mi][nj], 0, 0, 0);
        acc[mi][nj] = __builtin_amdgcn_mfma_f32_16x16x32_bf16(
            Al[mi], Bh[nj], acc[mi][nj], 0, 0, 0);
      }
  }

  const int fq = lane >> 4;
#pragma unroll
  for (int nj = 0; nj < 4; ++nj) {
    const int col = bn * 128 + wn * 64 + nj * 16 + fr;
    const float bias = bi[col];
#pragma unroll
    for (int mi = 0; mi < 4; ++mi)
#pragma unroll
      for (int reg = 0; reg < 4; ++reg) {
        const size_t row = (size_t)bm * 128 + wm * 64 + mi * 16 + fq * 4 + reg;
        out[row * H_ + col] = acc[mi][nj][reg] + bias;
      }
  }
}

// ---------------------------------------------------------------------------
// Kernel B v17 = R13 (best: 4.93 ms) + ONE change: xi[t+1] prefetch moved
// BEFORE the k-loop so its ~1us miss completes under the 16-kt MFMA pipeline
// instead of sitting between compute and the vmcnt(0) drain on the serial
// chain. [R16's 4-change bundle regressed (6.33 ms): per-wave flags + hot
// spin quadrupled poll pressure on MALL. R13's wave0-poll + syncthreads
// broadcast is the best tested release/poll structure — restored verbatim.]
// ---------------------------------------------------------------------------
__global__ __launch_bounds__(256, 1) void rnn_scan(
    const float* __restrict__ h0, const float* __restrict__ Wh,
    const float* __restrict__ bh, float* __restrict__ out,
    unsigned int* __restrict__ flags) {
  __shared__ unsigned short WhHi[32 * 1024];  // 64 KB
  __shared__ float red[2 * 32 * 17];          // 4.25 KB (stride-17)
  const int tid = threadIdx.x;
  const int g = blockIdx.x & 7;
  const int c = blockIdx.x >> 3;
  const int j0 = c << 5;
  const int b0 = g << 4;

  // ---- Stage Wh-hi rows j0..j0+31 into LDS (once) ----
#pragma unroll
  for (int i = 0; i < 16; ++i) {
    const int sid = i * 256 + tid;
    const int jr = sid >> 7;
    const int s = sid & 127;
    const float* p = &Wh[(size_t)(j0 + jr) * H_ + s * 8];
    const float4 u = *(const float4*)(p);
    const float4 v4 = *(const float4*)(p + 4);
    bf16x8 hi, lo;
    pack8(u, v4, hi, lo);
    *(bf16x8*)&WhHi[jr * 1024 + (s ^ (jr & 7)) * 8] = hi;
  }

  const int lane = tid & 63;
  const int wv = tid >> 6;
  const int jh = wv >> 1;          // j-half (0,1)
  const int kh = wv & 1;           // K-half (0,1)
  const int fr = lane & 15;
  const int kb = lane >> 4;
  const int frx7 = fr & 7;
  const int jrt = (jh * 16 + fr) * 1024;

  // ---- Wh-lo -> registers: 16 k-tiles x 8 bf16 per lane ----
  bf16x8 wlo[16];
  {
    const float* wrow = Wh + (size_t)(j0 + jh * 16 + fr) * H_ + kh * 512;
#pragma unroll
    for (int kt = 0; kt < 16; ++kt) {
      const float* p = wrow + kt * 32 + kb * 8;
      const float4 u = *(const float4*)(p);
      const float4 v4 = *(const float4*)(p + 4);
      bf16x8 hi;
      pack8(u, v4, hi, wlo[kt]);
    }
  }

  const int jf = tid & 31;
  const int bfh = tid >> 5;
  const float bias = bh[j0 + jf];
  unsigned int* gflags = flags + (g << 6);
  __syncthreads();

  const unsigned long long* h64 =
      (const unsigned long long*)(h0 + (size_t)b0 * H_);
  const size_t hoff64 = (size_t)fr * (H_ / 2) + kh * 256;
  const size_t obase0 = (size_t)(b0 + bfh) * H_ + (j0 + jf);
  const size_t obase1 = obase0 + (size_t)8 * H_;
  float xi0 = out[obase0];
  float xi1 = out[obase1];
  for (int t = 0; t < L_; ++t) {
    const size_t tB = (size_t)t * B_ * H_;
    const size_t nB = tB + (size_t)(t + 1 < L_ ? B_ * H_ : 0);
    // xi[t+1] prefetch EARLY (the one change vs R13): completes under the
    // k-loop; value exclusively ours until our own t+1 store; register carry.
    const float xin0 = out[nB + obase0];
    const float xin1 = out[nB + obase1];

    f32x4 acc = (f32x4){0.f, 0.f, 0.f, 0.f};
#pragma unroll
    for (int kt = 0; kt < 16; ++kt) {
      const size_t k64 = hoff64 + kt * 16 + kb * 4;
      const unsigned long long p0 = __hip_atomic_load(
          &h64[k64 + 0], __ATOMIC_RELAXED, __HIP_MEMORY_SCOPE_AGENT);
      const unsigned long long p1 = __hip_atomic_load(
          &h64[k64 + 1], __ATOMIC_RELAXED, __HIP_MEMORY_SCOPE_AGENT);
      const unsigned long long p2 = __hip_atomic_load(
          &h64[k64 + 2], __ATOMIC_RELAXED, __HIP_MEMORY_SCOPE_AGENT);
      const unsigned long long p3 = __hip_atomic_load(
          &h64[k64 + 3], __ATOMIC_RELAXED, __HIP_MEMORY_SCOPE_AGENT);
      const float4 u = make_float4(__uint_as_float((unsigned)p0),
                                   __uint_as_float((unsigned)(p0 >> 32)),
                                   __uint_as_float((unsigned)p1),
                                   __uint_as_float((unsigned)(p1 >> 32)));
      const float4 v4 = make_float4(__uint_as_float((unsigned)p2),
                                    __uint_as_float((unsigned)(p2 >> 32)),
                                    __uint_as_float((unsigned)p3),
                                    __uint_as_float((unsigned)(p3 >> 32)));
      bf16x8 Bh, Bl;
      pack8(u, v4, Bh, Bl);
      const int ps = (kh * 64 + kt * 4 + kb) ^ frx7;
      const bf16x8 Ah = *(const bf16x8*)&WhHi[jrt + ps * 8];
      acc = __builtin_amdgcn_mfma_f32_16x16x32_bf16(Ah, Bh, acc, 0, 0, 0);
      acc = __builtin_amdgcn_mfma_f32_16x16x32_bf16(Ah, Bl, acc, 0, 0, 0);
      acc = __builtin_amdgcn_mfma_f32_16x16x32_bf16(wlo[kt], Bh, acc, 0, 0, 0);
    }
#pragma unroll
    for (int r4 = 0; r4 < 4; ++r4)
      red[(kh * 32 + jh * 16 + kb * 4 + r4) * 17 + fr] = acc[r4];
    __syncthreads();
    {
      const float s0 = red[(jf) * 17 + bfh] + red[(32 + jf) * 17 + bfh];
      const float s1 = red[(jf) * 17 + bfh + 8] + red[(32 + jf) * 17 + bfh + 8];
      const float v0 = tanhf(s0 + xi0 + bias);
      const float v1 = tanhf(s1 + xi1 + bias);
      __hip_atomic_store(&out[tB + obase0], v0, __ATOMIC_RELAXED,
                         __HIP_MEMORY_SCOPE_AGENT);
      __hip_atomic_store(&out[tB + obase1], v1, __ATOMIC_RELAXED,
                         __HIP_MEMORY_SCOPE_AGENT);
    }

    if (t + 1 < L_) {
      // ---- release: drain, block done, publish (R13 verbatim) ----
      asm volatile("s_waitcnt vmcnt(0)" ::: "memory");
      __syncthreads();
      if (tid == 0)
        __hip_atomic_store(&gflags[c], (unsigned)(t + 1), __ATOMIC_RELAXED,
                           __HIP_MEMORY_SCOPE_AGENT);
      // ---- wave 0: poll the 32 group flags (lanes duplicated x2) ----
      if (tid < 64) {
        const unsigned tgt = (unsigned)(t + 1);
        while (true) {
          const unsigned f = __hip_atomic_load(&gflags[tid & 31],
                                               __ATOMIC_RELAXED,
                                               __HIP_MEMORY_SCOPE_AGENT);
          if (__all((int)(f >= tgt))) break;
          __builtin_amdgcn_s_sleep(1);
        }
      }
      __syncthreads();
    }
    xi0 = xin0;
    xi1 = xin1;
    h64 = (const unsigned long long*)(out + tB + (size_t)b0 * H_);
  }
}

// ---------------------------------------------------------------------------
extern "C" void kernel_launch(void* const* d_in, const int* in_sizes, int n_in,
                              void* d_out, int out_size, void* d_ws, size_t ws_size,
                              hipStream_t stream) {
  const float* x    = (const float*)d_in[0];
  const float* h0   = (const float*)d_in[1];
  const float* Wi_w = (const float*)d_in[2];
  const float* Wi_b = (const float*)d_in[3];
  const float* Wh_w = (const float*)d_in[4];
  const float* Wh_b = (const float*)d_in[5];
  float* out = (float*)d_out;
  unsigned int* flags = (unsigned int*)d_ws;

  // Phase 1: xi -> d_out (split-bf16 MFMA)
  hipLaunchKernelGGL(xi_gemm_mfma, dim3(512, 8), dim3(256), 0, stream,
                     x, Wi_w, Wi_b, out);

  // Zero the barrier flags (graph replays reuse d_ws; flags must start 0)
  hipMemsetAsync(d_ws, 0, 4096, stream);

  // Phase 2: cooperative scan — 256 blocks (1/CU), 8 groups x 32 blocks
  void* args[] = { (void*)&h0, (void*)&Wh_w, (void*)&Wh_b, (void*)&out, (void*)&flags };
  hipLaunchCooperativeKernel((void*)rnn_scan, dim3(256), dim3(256), args, 0, stream);
}

// Round 18
// 4698.796 us; speedup vs baseline: 2.3998x; 1.1537x over previous
//
#include <hip/hip_runtime.h>
#include <cmath>

#define L_ 512
#define B_ 128
#define D_ 1024
#define H_ 1024

typedef __attribute__((ext_vector_type(8))) short bf16x8;
typedef __attribute__((ext_vector_type(4))) float f32x4;

static __device__ __forceinline__ unsigned short f32_bf16_rn(float f) {
  unsigned u = __float_as_uint(f);
  u += 0x7FFFu + ((u >> 16) & 1u);
  return (unsigned short)(u >> 16);
}
static __device__ __forceinline__ float bf16_f32(unsigned short h) {
  return __uint_as_float(((unsigned)h) << 16);
}

static __device__ __forceinline__ void pack8(const float4& u, const float4& v,
                                             bf16x8& hi, bf16x8& lo) {
  float f[8] = {u.x, u.y, u.z, u.w, v.x, v.y, v.z, v.w};
#pragma unroll
  for (int i = 0; i < 8; ++i) {
    const unsigned short h = f32_bf16_rn(f[i]);
    hi[i] = (short)h;
    lo[i] = (short)f32_bf16_rn(f[i] - bf16_f32(h));
  }
}

// ---------------------------------------------------------------------------
// Kernel A: xi = x @ Wi^T + bi, split-bf16 3-MFMA. (unchanged — R7-proven)
// ---------------------------------------------------------------------------
__global__ __launch_bounds__(256) void xi_gemm_mfma(
    const float* __restrict__ x, const float* __restrict__ Wi,
    const float* __restrict__ bi, float* __restrict__ out) {
  __shared__ unsigned short Ahi[128 * 32], Alo[128 * 32];
  __shared__ unsigned short Bhi[128 * 32], Blo[128 * 32];
  const int tid = threadIdx.x;
  const int bm = blockIdx.x, bn = blockIdx.y;
  const int lane = tid & 63, wv = tid >> 6;
  const int wm = wv >> 1, wn = wv & 1;

  const float* Ag = x + (size_t)bm * 128 * D_;
  const float* Bg = Wi + (size_t)bn * 128 * D_;

  f32x4 acc[4][4];
#pragma unroll
  for (int mi = 0; mi < 4; ++mi)
#pragma unroll
    for (int nj = 0; nj < 4; ++nj) acc[mi][nj] = (f32x4){0.f, 0.f, 0.f, 0.f};

  const int r = tid >> 1;
  const int h2 = tid & 1;
  const int sw = r & 3;
  const int s0 = (h2 * 2) ^ sw, s1 = (h2 * 2 + 1) ^ sw;
  const int fr = lane & 15, kg = lane >> 4;

  for (int k0 = 0; k0 < D_; k0 += 32) {
    __syncthreads();
    {
      const float* pa = &Ag[(size_t)r * D_ + k0 + h2 * 16];
      const float* pb = &Bg[(size_t)r * D_ + k0 + h2 * 16];
      const float4 a0 = *(const float4*)(pa + 0), a1 = *(const float4*)(pa + 4);
      const float4 a2 = *(const float4*)(pa + 8), a3 = *(const float4*)(pa + 12);
      const float4 b0 = *(const float4*)(pb + 0), b1 = *(const float4*)(pb + 4);
      const float4 b2 = *(const float4*)(pb + 8), b3 = *(const float4*)(pb + 12);
      bf16x8 h, l;
      pack8(a0, a1, h, l);
      *(bf16x8*)&Ahi[r * 32 + s0 * 8] = h;
      *(bf16x8*)&Alo[r * 32 + s0 * 8] = l;
      pack8(a2, a3, h, l);
      *(bf16x8*)&Ahi[r * 32 + s1 * 8] = h;
      *(bf16x8*)&Alo[r * 32 + s1 * 8] = l;
      pack8(b0, b1, h, l);
      *(bf16x8*)&Bhi[r * 32 + s0 * 8] = h;
      *(bf16x8*)&Blo[r * 32 + s0 * 8] = l;
      pack8(b2, b3, h, l);
      *(bf16x8*)&Bhi[r * 32 + s1 * 8] = h;
      *(bf16x8*)&Blo[r * 32 + s1 * 8] = l;
    }
    __syncthreads();

    bf16x8 Ah[4], Al[4], Bh[4], Bl[4];
#pragma unroll
    for (int mi = 0; mi < 4; ++mi) {
      const int row = wm * 64 + mi * 16 + fr;
      const int sl = kg ^ (row & 3);
      Ah[mi] = *(const bf16x8*)&Ahi[row * 32 + sl * 8];
      Al[mi] = *(const bf16x8*)&Alo[row * 32 + sl * 8];
    }
#pragma unroll
    for (int nj = 0; nj < 4; ++nj) {
      const int row = wn * 64 + nj * 16 + fr;
      const int sl = kg ^ (row & 3);
      Bh[nj] = *(const bf16x8*)&Bhi[row * 32 + sl * 8];
      Bl[nj] = *(const bf16x8*)&Blo[row * 32 + sl * 8];
    }
#pragma unroll
    for (int mi = 0; mi < 4; ++mi)
#pragma unroll
      for (int nj = 0; nj < 4; ++nj) {
        acc[mi][nj] = __builtin_amdgcn_mfma_f32_16x16x32_bf16(
            Ah[mi], Bh[nj], acc[mi][nj], 0, 0, 0);
        acc[mi][nj] = __builtin_amdgcn_mfma_f32_16x16x32_bf16(
            Ah[mi], Bl[nj], acc[mi][nj], 0, 0, 0);
        acc[mi][nj] = __builtin_amdgcn_mfma_f32_16x16x32_bf16(
            Al[mi], Bh[nj], acc[mi][nj], 0, 0, 0);
      }
  }

  const int fq = lane >> 4;
#pragma unroll
  for (int nj = 0; nj < 4; ++nj) {
    const int col = bn * 128 + wn * 64 + nj * 16 + fr;
    const float bias = bi[col];
#pragma unroll
    for (int mi = 0; mi < 4; ++mi)
#pragma unroll
      for (int reg = 0; reg < 4; ++reg) {
        const size_t row = (size_t)bm * 128 + wm * 64 + mi * 16 + fq * 4 + reg;
        out[row * H_ + col] = acc[mi][nj][reg] + bias;
      }
  }
}

// ---------------------------------------------------------------------------
// Kernel B v18 = R17 + ONE change: h-loads are PLAIN CACHED (L2-served;
// each 64B h line fetched once per XCD from MALL instead of ~64 redundant
// bypass reads per group per step — bypass was ~32 MB/step of MALL-latency
// traffic on the critical path). Correctness: sc1 write-through h stores
// (unchanged) make h MALL-visible; the R10-proven wave-0 acquire fence
// after the poll invalidates L1/L2 so next-gen h reads re-miss to MALL.
// xi register-carry (R17) keeps xi safe across the invalidate.
// ---------------------------------------------------------------------------
__global__ __launch_bounds__(256, 1) void rnn_scan(
    const float* __restrict__ h0, const float* __restrict__ Wh,
    const float* __restrict__ bh, float* __restrict__ out,
    unsigned int* __restrict__ flags) {
  __shared__ unsigned short WhHi[32 * 1024];  // 64 KB
  __shared__ float red[2 * 32 * 17];          // 4.25 KB (stride-17)
  const int tid = threadIdx.x;
  const int g = blockIdx.x & 7;
  const int c = blockIdx.x >> 3;
  const int j0 = c << 5;
  const int b0 = g << 4;

  // ---- Stage Wh-hi rows j0..j0+31 into LDS (once) ----
#pragma unroll
  for (int i = 0; i < 16; ++i) {
    const int sid = i * 256 + tid;
    const int jr = sid >> 7;
    const int s = sid & 127;
    const float* p = &Wh[(size_t)(j0 + jr) * H_ + s * 8];
    const float4 u = *(const float4*)(p);
    const float4 v4 = *(const float4*)(p + 4);
    bf16x8 hi, lo;
    pack8(u, v4, hi, lo);
    *(bf16x8*)&WhHi[jr * 1024 + (s ^ (jr & 7)) * 8] = hi;
  }

  const int lane = tid & 63;
  const int wv = tid >> 6;
  const int jh = wv >> 1;          // j-half (0,1)
  const int kh = wv & 1;           // K-half (0,1)
  const int fr = lane & 15;
  const int kb = lane >> 4;
  const int frx7 = fr & 7;
  const int jrt = (jh * 16 + fr) * 1024;

  // ---- Wh-lo -> registers: 16 k-tiles x 8 bf16 per lane ----
  bf16x8 wlo[16];
  {
    const float* wrow = Wh + (size_t)(j0 + jh * 16 + fr) * H_ + kh * 512;
#pragma unroll
    for (int kt = 0; kt < 16; ++kt) {
      const float* p = wrow + kt * 32 + kb * 8;
      const float4 u = *(const float4*)(p);
      const float4 v4 = *(const float4*)(p + 4);
      bf16x8 hi;
      pack8(u, v4, hi, wlo[kt]);
    }
  }

  const int jf = tid & 31;
  const int bfh = tid >> 5;
  const float bias = bh[j0 + jf];
  unsigned int* gflags = flags + (g << 6);
  __syncthreads();

  const float* hbase = h0 + (size_t)b0 * H_;
  const size_t hoffF = (size_t)fr * H_ + kh * 512;
  const size_t obase0 = (size_t)(b0 + bfh) * H_ + (j0 + jf);
  const size_t obase1 = obase0 + (size_t)8 * H_;
  float xi0 = out[obase0];
  float xi1 = out[obase1];
  for (int t = 0; t < L_; ++t) {
    const size_t tB = (size_t)t * B_ * H_;
    const size_t nB = tB + (size_t)(t + 1 < L_ ? B_ * H_ : 0);
    // xi[t+1] prefetch early (R17): completes under the k-loop; register
    // carry survives the acquire invalidate.
    const float xin0 = out[nB + obase0];
    const float xin1 = out[nB + obase1];

    f32x4 acc = (f32x4){0.f, 0.f, 0.f, 0.f};
#pragma unroll
    for (int kt = 0; kt < 16; ++kt) {
      // PLAIN CACHED h loads (the one change): post-fence, first touch per
      // line misses to MALL, the rest of the XCD's readers hit L2.
      const float* hp = &hbase[hoffF + kt * 32 + kb * 8];
      const float4 u = *(const float4*)(hp);
      const float4 v4 = *(const float4*)(hp + 4);
      bf16x8 Bh, Bl;
      pack8(u, v4, Bh, Bl);
      const int ps = (kh * 64 + kt * 4 + kb) ^ frx7;
      const bf16x8 Ah = *(const bf16x8*)&WhHi[jrt + ps * 8];
      acc = __builtin_amdgcn_mfma_f32_16x16x32_bf16(Ah, Bh, acc, 0, 0, 0);
      acc = __builtin_amdgcn_mfma_f32_16x16x32_bf16(Ah, Bl, acc, 0, 0, 0);
      acc = __builtin_amdgcn_mfma_f32_16x16x32_bf16(wlo[kt], Bh, acc, 0, 0, 0);
    }
#pragma unroll
    for (int r4 = 0; r4 < 4; ++r4)
      red[(kh * 32 + jh * 16 + kb * 4 + r4) * 17 + fr] = acc[r4];
    __syncthreads();
    {
      const float s0 = red[(jf) * 17 + bfh] + red[(32 + jf) * 17 + bfh];
      const float s1 = red[(jf) * 17 + bfh + 8] + red[(32 + jf) * 17 + bfh + 8];
      const float v0 = tanhf(s0 + xi0 + bias);
      const float v1 = tanhf(s1 + xi1 + bias);
      // sc1 write-through: h must reach the MALL for cross-XCD visibility.
      __hip_atomic_store(&out[tB + obase0], v0, __ATOMIC_RELAXED,
                         __HIP_MEMORY_SCOPE_AGENT);
      __hip_atomic_store(&out[tB + obase1], v1, __ATOMIC_RELAXED,
                         __HIP_MEMORY_SCOPE_AGENT);
    }

    if (t + 1 < L_) {
      // ---- release: drain, block done, publish (R13 verbatim) ----
      asm volatile("s_waitcnt vmcnt(0)" ::: "memory");
      __syncthreads();
      if (tid == 0)
        __hip_atomic_store(&gflags[c], (unsigned)(t + 1), __ATOMIC_RELAXED,
                           __HIP_MEMORY_SCOPE_AGENT);
      // ---- wave 0: poll the 32 group flags, then ONE acquire fence ----
      if (tid < 64) {
        const unsigned tgt = (unsigned)(t + 1);
        while (true) {
          const unsigned f = __hip_atomic_load(&gflags[tid & 31],
                                               __ATOMIC_RELAXED,
                                               __HIP_MEMORY_SCOPE_AGENT);
          if (__all((int)(f >= tgt))) break;
          __builtin_amdgcn_s_sleep(1);
        }
        // R10-proven: one buffer_inv per block invalidates the CU's L1 and
        // the XCD's L2; __syncthreads orders the other waves behind it.
        __builtin_amdgcn_fence(__ATOMIC_ACQUIRE, "agent");
      }
      __syncthreads();
    }
    xi0 = xin0;
    xi1 = xin1;
    hbase = out + tB + (size_t)b0 * H_;
  }
}

// ---------------------------------------------------------------------------
extern "C" void kernel_launch(void* const* d_in, const int* in_sizes, int n_in,
                              void* d_out, int out_size, void* d_ws, size_t ws_size,
                              hipStream_t stream) {
  const float* x    = (const float*)d_in[0];
  const float* h0   = (const float*)d_in[1];
  const float* Wi_w = (const float*)d_in[2];
  const float* Wi_b = (const float*)d_in[3];
  const float* Wh_w = (const float*)d_in[4];
  const float* Wh_b = (const float*)d_in[5];
  float* out = (float*)d_out;
  unsigned int* flags = (unsigned int*)d_ws;

  // Phase 1: xi -> d_out (split-bf16 MFMA)
  hipLaunchKernelGGL(xi_gemm_mfma, dim3(512, 8), dim3(256), 0, stream,
                     x, Wi_w, Wi_b, out);

  // Zero the barrier flags (graph replays reuse d_ws; flags must start 0)
  hipMemsetAsync(d_ws, 0, 4096, stream);

  // Phase 2: cooperative scan — 256 blocks (1/CU), 8 groups x 32 blocks
  void* args[] = { (void*)&h0, (void*)&Wh_w, (void*)&Wh_b, (void*)&out, (void*)&flags };
  hipLaunchCooperativeKernel((void*)rnn_scan, dim3(256), dim3(256), args, 0, stream);
}

// Round 19
// 4645.219 us; speedup vs baseline: 2.4275x; 1.0115x over previous
//
#include <hip/hip_runtime.h>
#include <cmath>

#define L_ 512
#define B_ 128
#define D_ 1024
#define H_ 1024
#define PKN (B_ * H_)  // one packed-h buffer: 128K dwords = 512 KB

typedef __attribute__((ext_vector_type(8))) short bf16x8;
typedef __attribute__((ext_vector_type(4))) float f32x4;
typedef __attribute__((ext_vector_type(4))) unsigned uint4v;

static __device__ __forceinline__ unsigned short f32_bf16_rn(float f) {
  unsigned u = __float_as_uint(f);
  u += 0x7FFFu + ((u >> 16) & 1u);
  return (unsigned short)(u >> 16);
}
static __device__ __forceinline__ float bf16_f32(unsigned short h) {
  return __uint_as_float(((unsigned)h) << 16);
}

static __device__ __forceinline__ void pack8(const float4& u, const float4& v,
                                             bf16x8& hi, bf16x8& lo) {
  float f[8] = {u.x, u.y, u.z, u.w, v.x, v.y, v.z, v.w};
#pragma unroll
  for (int i = 0; i < 8; ++i) {
    const unsigned short h = f32_bf16_rn(f[i]);
    hi[i] = (short)h;
    lo[i] = (short)f32_bf16_rn(f[i] - bf16_f32(h));
  }
}

// ---------------------------------------------------------------------------
// Kernel A: xi = x @ Wi^T + bi, split-bf16 3-MFMA. (unchanged — R7-proven)
// ---------------------------------------------------------------------------
__global__ __launch_bounds__(256) void xi_gemm_mfma(
    const float* __restrict__ x, const float* __restrict__ Wi,
    const float* __restrict__ bi, float* __restrict__ out) {
  __shared__ unsigned short Ahi[128 * 32], Alo[128 * 32];
  __shared__ unsigned short Bhi[128 * 32], Blo[128 * 32];
  const int tid = threadIdx.x;
  const int bm = blockIdx.x, bn = blockIdx.y;
  const int lane = tid & 63, wv = tid >> 6;
  const int wm = wv >> 1, wn = wv & 1;

  const float* Ag = x + (size_t)bm * 128 * D_;
  const float* Bg = Wi + (size_t)bn * 128 * D_;

  f32x4 acc[4][4];
#pragma unroll
  for (int mi = 0; mi < 4; ++mi)
#pragma unroll
    for (int nj = 0; nj < 4; ++nj) acc[mi][nj] = (f32x4){0.f, 0.f, 0.f, 0.f};

  const int r = tid >> 1;
  const int h2 = tid & 1;
  const int sw = r & 3;
  const int s0 = (h2 * 2) ^ sw, s1 = (h2 * 2 + 1) ^ sw;
  const int fr = lane & 15, kg = lane >> 4;

  for (int k0 = 0; k0 < D_; k0 += 32) {
    __syncthreads();
    {
      const float* pa = &Ag[(size_t)r * D_ + k0 + h2 * 16];
      const float* pb = &Bg[(size_t)r * D_ + k0 + h2 * 16];
      const float4 a0 = *(const float4*)(pa + 0), a1 = *(const float4*)(pa + 4);
      const float4 a2 = *(const float4*)(pa + 8), a3 = *(const float4*)(pa + 12);
      const float4 b0 = *(const float4*)(pb + 0), b1 = *(const float4*)(pb + 4);
      const float4 b2 = *(const float4*)(pb + 8), b3 = *(const float4*)(pb + 12);
      bf16x8 h, l;
      pack8(a0, a1, h, l);
      *(bf16x8*)&Ahi[r * 32 + s0 * 8] = h;
      *(bf16x8*)&Alo[r * 32 + s0 * 8] = l;
      pack8(a2, a3, h, l);
      *(bf16x8*)&Ahi[r * 32 + s1 * 8] = h;
      *(bf16x8*)&Alo[r * 32 + s1 * 8] = l;
      pack8(b0, b1, h, l);
      *(bf16x8*)&Bhi[r * 32 + s0 * 8] = h;
      *(bf16x8*)&Blo[r * 32 + s0 * 8] = l;
      pack8(b2, b3, h, l);
      *(bf16x8*)&Bhi[r * 32 + s1 * 8] = h;
      *(bf16x8*)&Blo[r * 32 + s1 * 8] = l;
    }
    __syncthreads();

    bf16x8 Ah[4], Al[4], Bh[4], Bl[4];
#pragma unroll
    for (int mi = 0; mi < 4; ++mi) {
      const int row = wm * 64 + mi * 16 + fr;
      const int sl = kg ^ (row & 3);
      Ah[mi] = *(const bf16x8*)&Ahi[row * 32 + sl * 8];
      Al[mi] = *(const bf16x8*)&Alo[row * 32 + sl * 8];
    }
#pragma unroll
    for (int nj = 0; nj < 4; ++nj) {
      const int row = wn * 64 + nj * 16 + fr;
      const int sl = kg ^ (row & 3);
      Bh[nj] = *(const bf16x8*)&Bhi[row * 32 + sl * 8];
      Bl[nj] = *(const bf16x8*)&Blo[row * 32 + sl * 8];
    }
#pragma unroll
    for (int mi = 0; mi < 4; ++mi)
#pragma unroll
      for (int nj = 0; nj < 4; ++nj) {
        acc[mi][nj] = __builtin_amdgcn_mfma_f32_16x16x32_bf16(
            Ah[mi], Bh[nj], acc[mi][nj], 0, 0, 0);
        acc[mi][nj] = __builtin_amdgcn_mfma_f32_16x16x32_bf16(
            Ah[mi], Bl[nj], acc[mi][nj], 0, 0, 0);
        acc[mi][nj] = __builtin_amdgcn_mfma_f32_16x16x32_bf16(
            Al[mi], Bh[nj], acc[mi][nj], 0, 0, 0);
      }
  }

  const int fq = lane >> 4;
#pragma unroll
  for (int nj = 0; nj < 4; ++nj) {
    const int col = bn * 128 + wn * 64 + nj * 16 + fr;
    const float bias = bi[col];
#pragma unroll
    for (int mi = 0; mi < 4; ++mi)
#pragma unroll
      for (int reg = 0; reg < 4; ++reg) {
        const size_t row = (size_t)bm * 128 + wm * 64 + mi * 16 + fq * 4 + reg;
        out[row * H_ + col] = acc[mi][nj][reg] + bias;
      }
  }
}

// ---------------------------------------------------------------------------
// Kernel B v19 = R18 (cached h + wave-0 acquire fence; 4.07 ms) + R14's
// producer-packed exchange (both individually validated):
//
//  * Finisher packs h as (bf16hi<<16|lo) into pk ping-pong (write t&1, read
//    (t-1)&1). pk stores are sc1 write-through, drained by the existing
//    vmcnt(0) before flag publish.
//  * Consumers read pk with PLAIN CACHED u64 loads (the R18 lesson: L2
//    serves repeats, only first touch per line goes to MALL) + v_perm
//    unpack (8 VALU/kt vs pack8's 80 — removes the dependent-chain VALU
//    that R18 re-exposed, VALUBusy 20.9%). Halves exchange bytes.
//  * Staleness: the R18 wave-0 acquire fence (buffer_inv) after the poll
//    covers pk exactly as it covered h. Generation safety: full-group
//    barrier + publish-after-vmcnt(0) (drains loads) — R14/R16-passing
//    argument. t=0 keeps the f32-h0 + pack8 path.
// ---------------------------------------------------------------------------
__global__ __launch_bounds__(256, 1) void rnn_scan(
    const float* __restrict__ h0, const float* __restrict__ Wh,
    const float* __restrict__ bh, float* __restrict__ out,
    unsigned int* __restrict__ flags, unsigned int* __restrict__ pk) {
  __shared__ unsigned short WhHi[32 * 1024];  // 64 KB
  __shared__ float red[2 * 32 * 17];          // 4.25 KB (stride-17)
  const int tid = threadIdx.x;
  const int g = blockIdx.x & 7;
  const int c = blockIdx.x >> 3;
  const int j0 = c << 5;
  const int b0 = g << 4;

  // ---- Stage Wh-hi rows j0..j0+31 into LDS (once) ----
#pragma unroll
  for (int i = 0; i < 16; ++i) {
    const int sid = i * 256 + tid;
    const int jr = sid >> 7;
    const int s = sid & 127;
    const float* p = &Wh[(size_t)(j0 + jr) * H_ + s * 8];
    const float4 u = *(const float4*)(p);
    const float4 v4 = *(const float4*)(p + 4);
    bf16x8 hi, lo;
    pack8(u, v4, hi, lo);
    *(bf16x8*)&WhHi[jr * 1024 + (s ^ (jr & 7)) * 8] = hi;
  }

  const int lane = tid & 63;
  const int wv = tid >> 6;
  const int jh = wv >> 1;          // j-half (0,1)
  const int kh = wv & 1;           // K-half (0,1)
  const int fr = lane & 15;
  const int kb = lane >> 4;
  const int frx7 = fr & 7;
  const int jrt = (jh * 16 + fr) * 1024;

  // ---- Wh-lo -> registers: 16 k-tiles x 8 bf16 per lane ----
  bf16x8 wlo[16];
  {
    const float* wrow = Wh + (size_t)(j0 + jh * 16 + fr) * H_ + kh * 512;
#pragma unroll
    for (int kt = 0; kt < 16; ++kt) {
      const float* p = wrow + kt * 32 + kb * 8;
      const float4 u = *(const float4*)(p);
      const float4 v4 = *(const float4*)(p + 4);
      bf16x8 hi;
      pack8(u, v4, hi, wlo[kt]);
    }
  }

  const int jf = tid & 31;
  const int bfh = tid >> 5;
  const float bias = bh[j0 + jf];
  unsigned int* gflags = flags + (g << 6);
  __syncthreads();

  const size_t hoffF = (size_t)fr * H_ + kh * 512;
  const size_t obase0 = (size_t)(b0 + bfh) * H_ + (j0 + jf);
  const size_t obase1 = obase0 + (size_t)8 * H_;
  float xi0 = out[obase0];
  float xi1 = out[obase1];
  for (int t = 0; t < L_; ++t) {
    const size_t tB = (size_t)t * B_ * H_;
    const size_t nB = tB + (size_t)(t + 1 < L_ ? B_ * H_ : 0);
    // xi[t+1] prefetch early (R17): completes under the k-loop; register
    // carry survives the acquire invalidate.
    const float xin0 = out[nB + obase0];
    const float xin1 = out[nB + obase1];

    f32x4 acc = (f32x4){0.f, 0.f, 0.f, 0.f};
    if (t == 0) {
      // f32 h0 (immutable input) + consumer-side pack
      const float* hb = h0 + (size_t)b0 * H_ + hoffF;
#pragma unroll
      for (int kt = 0; kt < 16; ++kt) {
        const float* hp = hb + kt * 32 + kb * 8;
        const float4 u = *(const float4*)(hp);
        const float4 v4 = *(const float4*)(hp + 4);
        bf16x8 Bh, Bl;
        pack8(u, v4, Bh, Bl);
        const int ps = (kh * 64 + kt * 4 + kb) ^ frx7;
        const bf16x8 Ah = *(const bf16x8*)&WhHi[jrt + ps * 8];
        acc = __builtin_amdgcn_mfma_f32_16x16x32_bf16(Ah, Bh, acc, 0, 0, 0);
        acc = __builtin_amdgcn_mfma_f32_16x16x32_bf16(Ah, Bl, acc, 0, 0, 0);
        acc = __builtin_amdgcn_mfma_f32_16x16x32_bf16(wlo[kt], Bh, acc, 0, 0, 0);
      }
    } else {
      // producer-packed path: plain CACHED u64 loads + v_perm unpack
      const unsigned long long* pk64 = (const unsigned long long*)(
          pk + (size_t)((t + 1) & 1) * PKN + (size_t)b0 * H_ + hoffF);
      const size_t pko = (size_t)kb * 4;
#pragma unroll
      for (int kt = 0; kt < 16; ++kt) {
        const size_t k64 = pko + kt * 16;
        const unsigned long long q0 = pk64[k64 + 0];
        const unsigned long long q1 = pk64[k64 + 1];
        const unsigned long long q2 = pk64[k64 + 2];
        const unsigned long long q3 = pk64[k64 + 3];
        const unsigned u0 = (unsigned)q0, u1 = (unsigned)(q0 >> 32);
        const unsigned u2 = (unsigned)q1, u3 = (unsigned)(q1 >> 32);
        const unsigned u4 = (unsigned)q2, u5 = (unsigned)(q2 >> 32);
        const unsigned u6 = (unsigned)q3, u7 = (unsigned)(q3 >> 32);
        union { uint4v u; bf16x8 v; } ch, cl;
        ch.u.x = __builtin_amdgcn_perm(u1, u0, 0x07060302u);
        ch.u.y = __builtin_amdgcn_perm(u3, u2, 0x07060302u);
        ch.u.z = __builtin_amdgcn_perm(u5, u4, 0x07060302u);
        ch.u.w = __builtin_amdgcn_perm(u7, u6, 0x07060302u);
        cl.u.x = __builtin_amdgcn_perm(u1, u0, 0x05040100u);
        cl.u.y = __builtin_amdgcn_perm(u3, u2, 0x05040100u);
        cl.u.z = __builtin_amdgcn_perm(u5, u4, 0x05040100u);
        cl.u.w = __builtin_amdgcn_perm(u7, u6, 0x05040100u);
        const int ps = (kh * 64 + kt * 4 + kb) ^ frx7;
        const bf16x8 Ah = *(const bf16x8*)&WhHi[jrt + ps * 8];
        acc = __builtin_amdgcn_mfma_f32_16x16x32_bf16(Ah, ch.v, acc, 0, 0, 0);
        acc = __builtin_amdgcn_mfma_f32_16x16x32_bf16(Ah, cl.v, acc, 0, 0, 0);
        acc = __builtin_amdgcn_mfma_f32_16x16x32_bf16(wlo[kt], ch.v, acc, 0, 0, 0);
      }
    }
#pragma unroll
    for (int r4 = 0; r4 < 4; ++r4)
      red[(kh * 32 + jh * 16 + kb * 4 + r4) * 17 + fr] = acc[r4];
    __syncthreads();
    {
      const float s0 = red[(jf) * 17 + bfh] + red[(32 + jf) * 17 + bfh];
      const float s1 = red[(jf) * 17 + bfh + 8] + red[(32 + jf) * 17 + bfh + 8];
      const float v0 = tanhf(s0 + xi0 + bias);
      const float v1 = tanhf(s1 + xi1 + bias);
      // out: sc1 write-through (R18 anchor)
      __hip_atomic_store(&out[tB + obase0], v0, __ATOMIC_RELAXED,
                         __HIP_MEMORY_SCOPE_AGENT);
      __hip_atomic_store(&out[tB + obase1], v1, __ATOMIC_RELAXED,
                         __HIP_MEMORY_SCOPE_AGENT);
      // pk: producer-side pack, sc1 write-through (the exchange payload)
      unsigned int* pkw = pk + (size_t)(t & 1) * PKN;
      const unsigned short h0p = f32_bf16_rn(v0);
      const unsigned short l0p = f32_bf16_rn(v0 - bf16_f32(h0p));
      const unsigned short h1p = f32_bf16_rn(v1);
      const unsigned short l1p = f32_bf16_rn(v1 - bf16_f32(h1p));
      __hip_atomic_store(&pkw[obase0], ((unsigned)h0p << 16) | l0p,
                         __ATOMIC_RELAXED, __HIP_MEMORY_SCOPE_AGENT);
      __hip_atomic_store(&pkw[obase1], ((unsigned)h1p << 16) | l1p,
                         __ATOMIC_RELAXED, __HIP_MEMORY_SCOPE_AGENT);
    }

    if (t + 1 < L_) {
      // ---- release: drain, block done, publish (R13 verbatim) ----
      asm volatile("s_waitcnt vmcnt(0)" ::: "memory");
      __syncthreads();
      if (tid == 0)
        __hip_atomic_store(&gflags[c], (unsigned)(t + 1), __ATOMIC_RELAXED,
                           __HIP_MEMORY_SCOPE_AGENT);
      // ---- wave 0: poll the 32 group flags, then ONE acquire fence ----
      if (tid < 64) {
        const unsigned tgt = (unsigned)(t + 1);
        while (true) {
          const unsigned f = __hip_atomic_load(&gflags[tid & 31],
                                               __ATOMIC_RELAXED,
                                               __HIP_MEMORY_SCOPE_AGENT);
          if (__all((int)(f >= tgt))) break;
          __builtin_amdgcn_s_sleep(1);
        }
        // One buffer_inv per block (R10/R18-proven placement): invalidates
        // L1 + XCD L2 so next-gen pk/h reads re-miss to MALL.
        __builtin_amdgcn_fence(__ATOMIC_ACQUIRE, "agent");
      }
      __syncthreads();
    }
    xi0 = xin0;
    xi1 = xin1;
  }
}

// ---------------------------------------------------------------------------
extern "C" void kernel_launch(void* const* d_in, const int* in_sizes, int n_in,
                              void* d_out, int out_size, void* d_ws, size_t ws_size,
                              hipStream_t stream) {
  const float* x    = (const float*)d_in[0];
  const float* h0   = (const float*)d_in[1];
  const float* Wi_w = (const float*)d_in[2];
  const float* Wi_b = (const float*)d_in[3];
  const float* Wh_w = (const float*)d_in[4];
  const float* Wh_b = (const float*)d_in[5];
  float* out = (float*)d_out;
  unsigned int* flags = (unsigned int*)d_ws;                 // 4 KB
  unsigned int* pk = (unsigned int*)((char*)d_ws + 4096);    // 2 x 512 KB

  // Phase 1: xi -> d_out (split-bf16 MFMA)
  hipLaunchKernelGGL(xi_gemm_mfma, dim3(512, 8), dim3(256), 0, stream,
                     x, Wi_w, Wi_b, out);

  // Zero the barrier flags (graph replays reuse d_ws; flags must start 0)
  hipMemsetAsync(d_ws, 0, 4096, stream);

  // Phase 2: cooperative scan — 256 blocks (1/CU), packed cached exchange
  void* args[] = { (void*)&h0, (void*)&Wh_w, (void*)&Wh_b, (void*)&out,
                   (void*)&flags, (void*)&pk };
  hipLaunchCooperativeKernel((void*)rnn_scan, dim3(256), dim3(256), args, 0, stream);
}

// Round 21
// 4584.831 us; speedup vs baseline: 2.4594x; 1.0132x over previous
//
#include <hip/hip_runtime.h>
#include <cmath>

#define L_ 512
#define B_ 128
#define D_ 1024
#define H_ 1024
#define PKN (B_ * H_)  // one packed-h buffer: 128K dwords = 512 KB

typedef __attribute__((ext_vector_type(8))) short bf16x8;
typedef __attribute__((ext_vector_type(4))) float f32x4;
typedef __attribute__((ext_vector_type(4))) unsigned uint4v;

static __device__ __forceinline__ unsigned short f32_bf16_rn(float f) {
  unsigned u = __float_as_uint(f);
  u += 0x7FFFu + ((u >> 16) & 1u);
  return (unsigned short)(u >> 16);
}
static __device__ __forceinline__ float bf16_f32(unsigned short h) {
  return __uint_as_float(((unsigned)h) << 16);
}

static __device__ __forceinline__ void pack8(const float4& u, const float4& v,
                                             bf16x8& hi, bf16x8& lo) {
  float f[8] = {u.x, u.y, u.z, u.w, v.x, v.y, v.z, v.w};
#pragma unroll
  for (int i = 0; i < 8; ++i) {
    const unsigned short h = f32_bf16_rn(f[i]);
    hi[i] = (short)h;
    lo[i] = (short)f32_bf16_rn(f[i] - bf16_f32(h));
  }
}

// ---------------------------------------------------------------------------
// pack_wi: one-time split of Wi (1024x1024 f32) into bf16 hi/lo arrays.
// Bit-identical to the per-block pack8 it replaces. ~30 us.
// ---------------------------------------------------------------------------
__global__ __launch_bounds__(256) void pack_wi(
    const float* __restrict__ W, unsigned short* __restrict__ hi,
    unsigned short* __restrict__ lo) {
  const size_t i = ((size_t)blockIdx.x * 256 + threadIdx.x) * 8;
  const float4 u = *(const float4*)&W[i];
  const float4 v = *(const float4*)&W[i + 4];
  bf16x8 h, l;
  pack8(u, v, h, l);
  *(bf16x8*)&hi[i] = h;
  *(bf16x8*)&lo[i] = l;
}

// ---------------------------------------------------------------------------
// Kernel A: xi = x @ Wi^T + bi, split-bf16 3-MFMA.
// template<PRE>: PRE=1 reads pre-packed Wi (pure copy staging, half bytes,
// zero pack VALU for B); PRE=0 is the R7-proven in-kernel pack fallback
// (used when ws_size can't hold the 4 MB packed Wi).
// ---------------------------------------------------------------------------
template <int PRE>
__global__ __launch_bounds__(256) void xi_gemm_mfma_t(
    const float* __restrict__ x, const float* __restrict__ Wi,
    const float* __restrict__ bi, float* __restrict__ out,
    const unsigned short* __restrict__ wihi,
    const unsigned short* __restrict__ wilo) {
  __shared__ unsigned short Ahi[128 * 32], Alo[128 * 32];
  __shared__ unsigned short Bhi[128 * 32], Blo[128 * 32];
  const int tid = threadIdx.x;
  const int bm = blockIdx.x, bn = blockIdx.y;
  const int lane = tid & 63, wv = tid >> 6;
  const int wm = wv >> 1, wn = wv & 1;

  const float* Ag = x + (size_t)bm * 128 * D_;
  const float* Bg = Wi + (size_t)bn * 128 * D_;

  f32x4 acc[4][4];
#pragma unroll
  for (int mi = 0; mi < 4; ++mi)
#pragma unroll
    for (int nj = 0; nj < 4; ++nj) acc[mi][nj] = (f32x4){0.f, 0.f, 0.f, 0.f};

  const int r = tid >> 1;
  const int h2 = tid & 1;
  const int sw = r & 3;
  const int s0 = (h2 * 2) ^ sw, s1 = (h2 * 2 + 1) ^ sw;
  const int fr = lane & 15, kg = lane >> 4;

  for (int k0 = 0; k0 < D_; k0 += 32) {
    __syncthreads();
    {
      // A (x): f32 load + in-kernel split (unavoidable: x is huge)
      const float* pa = &Ag[(size_t)r * D_ + k0 + h2 * 16];
      const float4 a0 = *(const float4*)(pa + 0), a1 = *(const float4*)(pa + 4);
      const float4 a2 = *(const float4*)(pa + 8), a3 = *(const float4*)(pa + 12);
      bf16x8 h, l;
      pack8(a0, a1, h, l);
      *(bf16x8*)&Ahi[r * 32 + s0 * 8] = h;
      *(bf16x8*)&Alo[r * 32 + s0 * 8] = l;
      pack8(a2, a3, h, l);
      *(bf16x8*)&Ahi[r * 32 + s1 * 8] = h;
      *(bf16x8*)&Alo[r * 32 + s1 * 8] = l;
      if constexpr (PRE) {
        // B (Wi): pre-packed bf16 — pure 16B copies, no math
        const size_t wro = (size_t)(bn * 128 + r) * 1024 + k0 + h2 * 16;
        const unsigned short* ph = wihi + wro;
        const unsigned short* pl = wilo + wro;
        *(bf16x8*)&Bhi[r * 32 + s0 * 8] = *(const bf16x8*)(ph);
        *(bf16x8*)&Bhi[r * 32 + s1 * 8] = *(const bf16x8*)(ph + 8);
        *(bf16x8*)&Blo[r * 32 + s0 * 8] = *(const bf16x8*)(pl);
        *(bf16x8*)&Blo[r * 32 + s1 * 8] = *(const bf16x8*)(pl + 8);
      } else {
        const float* pb = &Bg[(size_t)r * D_ + k0 + h2 * 16];
        const float4 b0 = *(const float4*)(pb + 0), b1 = *(const float4*)(pb + 4);
        const float4 b2 = *(const float4*)(pb + 8), b3 = *(const float4*)(pb + 12);
        pack8(b0, b1, h, l);
        *(bf16x8*)&Bhi[r * 32 + s0 * 8] = h;
        *(bf16x8*)&Blo[r * 32 + s0 * 8] = l;
        pack8(b2, b3, h, l);
        *(bf16x8*)&Bhi[r * 32 + s1 * 8] = h;
        *(bf16x8*)&Blo[r * 32 + s1 * 8] = l;
      }
    }
    __syncthreads();

    bf16x8 Ah[4], Al[4], Bh[4], Bl[4];
#pragma unroll
    for (int mi = 0; mi < 4; ++mi) {
      const int row = wm * 64 + mi * 16 + fr;
      const int sl = kg ^ (row & 3);
      Ah[mi] = *(const bf16x8*)&Ahi[row * 32 + sl * 8];
      Al[mi] = *(const bf16x8*)&Alo[row * 32 + sl * 8];
    }
#pragma unroll
    for (int nj = 0; nj < 4; ++nj) {
      const int row = wn * 64 + nj * 16 + fr;
      const int sl = kg ^ (row & 3);
      Bh[nj] = *(const bf16x8*)&Bhi[row * 32 + sl * 8];
      Bl[nj] = *(const bf16x8*)&Blo[row * 32 + sl * 8];
    }
#pragma unroll
    for (int mi = 0; mi < 4; ++mi)
#pragma unroll
      for (int nj = 0; nj < 4; ++nj) {
        acc[mi][nj] = __builtin_amdgcn_mfma_f32_16x16x32_bf16(
            Ah[mi], Bh[nj], acc[mi][nj], 0, 0, 0);
        acc[mi][nj] = __builtin_amdgcn_mfma_f32_16x16x32_bf16(
            Ah[mi], Bl[nj], acc[mi][nj], 0, 0, 0);
        acc[mi][nj] = __builtin_amdgcn_mfma_f32_16x16x32_bf16(
            Al[mi], Bh[nj], acc[mi][nj], 0, 0, 0);
      }
  }

  const int fq = lane >> 4;
#pragma unroll
  for (int nj = 0; nj < 4; ++nj) {
    const int col = bn * 128 + wn * 64 + nj * 16 + fr;
    const float bias = bi[col];
#pragma unroll
    for (int mi = 0; mi < 4; ++mi)
#pragma unroll
      for (int reg = 0; reg < 4; ++reg) {
        const size_t row = (size_t)bm * 128 + wm * 64 + mi * 16 + fq * 4 + reg;
        out[row * H_ + col] = acc[mi][nj][reg] + bias;
      }
  }
}

// ---------------------------------------------------------------------------
// Kernel B: rnn_scan — VERBATIM R19 (4.08 ms, proven). No changes.
// [R20 post-mortem: the XCD fast path (plain flag stores + sc0 polls)
//  deadlocked -> timeout. Sync semantics are FROZEN to this proven set:
//  sc1 write-through stores, vmcnt(0) drain, block barrier, tid0 sc1 flag,
//  wave-0 agent poll, one agent acquire fence (buffer_inv) per block.]
// ---------------------------------------------------------------------------
__global__ __launch_bounds__(256, 1) void rnn_scan(
    const float* __restrict__ h0, const float* __restrict__ Wh,
    const float* __restrict__ bh, float* __restrict__ out,
    unsigned int* __restrict__ flags, unsigned int* __restrict__ pk) {
  __shared__ unsigned short WhHi[32 * 1024];  // 64 KB
  __shared__ float red[2 * 32 * 17];          // 4.25 KB (stride-17)
  const int tid = threadIdx.x;
  const int g = blockIdx.x & 7;
  const int c = blockIdx.x >> 3;
  const int j0 = c << 5;
  const int b0 = g << 4;

  // ---- Stage Wh-hi rows j0..j0+31 into LDS (once) ----
#pragma unroll
  for (int i = 0; i < 16; ++i) {
    const int sid = i * 256 + tid;
    const int jr = sid >> 7;
    const int s = sid & 127;
    const float* p = &Wh[(size_t)(j0 + jr) * H_ + s * 8];
    const float4 u = *(const float4*)(p);
    const float4 v4 = *(const float4*)(p + 4);
    bf16x8 hi, lo;
    pack8(u, v4, hi, lo);
    *(bf16x8*)&WhHi[jr * 1024 + (s ^ (jr & 7)) * 8] = hi;
  }

  const int lane = tid & 63;
  const int wv = tid >> 6;
  const int jh = wv >> 1;          // j-half (0,1)
  const int kh = wv & 1;           // K-half (0,1)
  const int fr = lane & 15;
  const int kb = lane >> 4;
  const int frx7 = fr & 7;
  const int jrt = (jh * 16 + fr) * 1024;

  // ---- Wh-lo -> registers: 16 k-tiles x 8 bf16 per lane ----
  bf16x8 wlo[16];
  {
    const float* wrow = Wh + (size_t)(j0 + jh * 16 + fr) * H_ + kh * 512;
#pragma unroll
    for (int kt = 0; kt < 16; ++kt) {
      const float* p = wrow + kt * 32 + kb * 8;
      const float4 u = *(const float4*)(p);
      const float4 v4 = *(const float4*)(p + 4);
      bf16x8 hi;
      pack8(u, v4, hi, wlo[kt]);
    }
  }

  const int jf = tid & 31;
  const int bfh = tid >> 5;
  const float bias = bh[j0 + jf];
  unsigned int* gflags = flags + (g << 6);
  __syncthreads();

  const size_t hoffF = (size_t)fr * H_ + kh * 512;
  const size_t obase0 = (size_t)(b0 + bfh) * H_ + (j0 + jf);
  const size_t obase1 = obase0 + (size_t)8 * H_;
  float xi0 = out[obase0];
  float xi1 = out[obase1];
  for (int t = 0; t < L_; ++t) {
    const size_t tB = (size_t)t * B_ * H_;
    const size_t nB = tB + (size_t)(t + 1 < L_ ? B_ * H_ : 0);
    // xi[t+1] prefetch early (R17): completes under the k-loop; register
    // carry survives the acquire invalidate.
    const float xin0 = out[nB + obase0];
    const float xin1 = out[nB + obase1];

    f32x4 acc = (f32x4){0.f, 0.f, 0.f, 0.f};
    if (t == 0) {
      // f32 h0 (immutable input) + consumer-side pack
      const float* hb = h0 + (size_t)b0 * H_ + hoffF;
#pragma unroll
      for (int kt = 0; kt < 16; ++kt) {
        const float* hp = hb + kt * 32 + kb * 8;
        const float4 u = *(const float4*)(hp);
        const float4 v4 = *(const float4*)(hp + 4);
        bf16x8 Bh, Bl;
        pack8(u, v4, Bh, Bl);
        const int ps = (kh * 64 + kt * 4 + kb) ^ frx7;
        const bf16x8 Ah = *(const bf16x8*)&WhHi[jrt + ps * 8];
        acc = __builtin_amdgcn_mfma_f32_16x16x32_bf16(Ah, Bh, acc, 0, 0, 0);
        acc = __builtin_amdgcn_mfma_f32_16x16x32_bf16(Ah, Bl, acc, 0, 0, 0);
        acc = __builtin_amdgcn_mfma_f32_16x16x32_bf16(wlo[kt], Bh, acc, 0, 0, 0);
      }
    } else {
      // producer-packed path: plain CACHED u64 loads + v_perm unpack
      const unsigned long long* pk64 = (const unsigned long long*)(
          pk + (size_t)((t + 1) & 1) * PKN + (size_t)b0 * H_ + hoffF);
      const size_t pko = (size_t)kb * 4;
#pragma unroll
      for (int kt = 0; kt < 16; ++kt) {
        const size_t k64 = pko + kt * 16;
        const unsigned long long q0 = pk64[k64 + 0];
        const unsigned long long q1 = pk64[k64 + 1];
        const unsigned long long q2 = pk64[k64 + 2];
        const unsigned long long q3 = pk64[k64 + 3];
        const unsigned u0 = (unsigned)q0, u1 = (unsigned)(q0 >> 32);
        const unsigned u2 = (unsigned)q1, u3 = (unsigned)(q1 >> 32);
        const unsigned u4 = (unsigned)q2, u5 = (unsigned)(q2 >> 32);
        const unsigned u6 = (unsigned)q3, u7 = (unsigned)(q3 >> 32);
        union { uint4v u; bf16x8 v; } ch, cl;
        ch.u.x = __builtin_amdgcn_perm(u1, u0, 0x07060302u);
        ch.u.y = __builtin_amdgcn_perm(u3, u2, 0x07060302u);
        ch.u.z = __builtin_amdgcn_perm(u5, u4, 0x07060302u);
        ch.u.w = __builtin_amdgcn_perm(u7, u6, 0x07060302u);
        cl.u.x = __builtin_amdgcn_perm(u1, u0, 0x05040100u);
        cl.u.y = __builtin_amdgcn_perm(u3, u2, 0x05040100u);
        cl.u.z = __builtin_amdgcn_perm(u5, u4, 0x05040100u);
        cl.u.w = __builtin_amdgcn_perm(u7, u6, 0x05040100u);
        const int ps = (kh * 64 + kt * 4 + kb) ^ frx7;
        const bf16x8 Ah = *(const bf16x8*)&WhHi[jrt + ps * 8];
        acc = __builtin_amdgcn_mfma_f32_16x16x32_bf16(Ah, ch.v, acc, 0, 0, 0);
        acc = __builtin_amdgcn_mfma_f32_16x16x32_bf16(Ah, cl.v, acc, 0, 0, 0);
        acc = __builtin_amdgcn_mfma_f32_16x16x32_bf16(wlo[kt], ch.v, acc, 0, 0, 0);
      }
    }
#pragma unroll
    for (int r4 = 0; r4 < 4; ++r4)
      red[(kh * 32 + jh * 16 + kb * 4 + r4) * 17 + fr] = acc[r4];
    __syncthreads();
    {
      const float s0 = red[(jf) * 17 + bfh] + red[(32 + jf) * 17 + bfh];
      const float s1 = red[(jf) * 17 + bfh + 8] + red[(32 + jf) * 17 + bfh + 8];
      const float v0 = tanhf(s0 + xi0 + bias);
      const float v1 = tanhf(s1 + xi1 + bias);
      // out: sc1 write-through (R18 anchor)
      __hip_atomic_store(&out[tB + obase0], v0, __ATOMIC_RELAXED,
                         __HIP_MEMORY_SCOPE_AGENT);
      __hip_atomic_store(&out[tB + obase1], v1, __ATOMIC_RELAXED,
                         __HIP_MEMORY_SCOPE_AGENT);
      // pk: producer-side pack, sc1 write-through (the exchange payload)
      unsigned int* pkw = pk + (size_t)(t & 1) * PKN;
      const unsigned short h0p = f32_bf16_rn(v0);
      const unsigned short l0p = f32_bf16_rn(v0 - bf16_f32(h0p));
      const unsigned short h1p = f32_bf16_rn(v1);
      const unsigned short l1p = f32_bf16_rn(v1 - bf16_f32(h1p));
      __hip_atomic_store(&pkw[obase0], ((unsigned)h0p << 16) | l0p,
                         __ATOMIC_RELAXED, __HIP_MEMORY_SCOPE_AGENT);
      __hip_atomic_store(&pkw[obase1], ((unsigned)h1p << 16) | l1p,
                         __ATOMIC_RELAXED, __HIP_MEMORY_SCOPE_AGENT);
    }

    if (t + 1 < L_) {
      // ---- release: drain, block done, publish (R13 verbatim) ----
      asm volatile("s_waitcnt vmcnt(0)" ::: "memory");
      __syncthreads();
      if (tid == 0)
        __hip_atomic_store(&gflags[c], (unsigned)(t + 1), __ATOMIC_RELAXED,
                           __HIP_MEMORY_SCOPE_AGENT);
      // ---- wave 0: poll the 32 group flags, then ONE acquire fence ----
      if (tid < 64) {
        const unsigned tgt = (unsigned)(t + 1);
        while (true) {
          const unsigned f = __hip_atomic_load(&gflags[tid & 31],
                                               __ATOMIC_RELAXED,
                                               __HIP_MEMORY_SCOPE_AGENT);
          if (__all((int)(f >= tgt))) break;
          __builtin_amdgcn_s_sleep(1);
        }
        // One buffer_inv per block (R10/R18-proven placement): invalidates
        // L1 + XCD L2 so next-gen pk/h reads re-miss to MALL.
        __builtin_amdgcn_fence(__ATOMIC_ACQUIRE, "agent");
      }
      __syncthreads();
    }
    xi0 = xin0;
    xi1 = xin1;
  }
}

// ---------------------------------------------------------------------------
extern "C" void kernel_launch(void* const* d_in, const int* in_sizes, int n_in,
                              void* d_out, int out_size, void* d_ws, size_t ws_size,
                              hipStream_t stream) {
  const float* x    = (const float*)d_in[0];
  const float* h0   = (const float*)d_in[1];
  const float* Wi_w = (const float*)d_in[2];
  const float* Wi_b = (const float*)d_in[3];
  const float* Wh_w = (const float*)d_in[4];
  const float* Wh_b = (const float*)d_in[5];
  float* out = (float*)d_out;
  unsigned int* flags = (unsigned int*)d_ws;                 // 4 KB
  unsigned int* pk = (unsigned int*)((char*)d_ws + 4096);    // 2 x 512 KB
  unsigned short* wihi =
      (unsigned short*)((char*)d_ws + 4096 + 2 * (size_t)PKN * 4);
  unsigned short* wilo = wihi + (size_t)H_ * D_;
  const size_t need = 4096 + 2 * (size_t)PKN * 4 + 2 * (size_t)H_ * D_ * 2;
  const bool pre = ws_size >= need;

  // Phase 1: xi -> d_out (split-bf16 MFMA; Wi pre-packed if ws allows)
  if (pre) {
    hipLaunchKernelGGL(pack_wi, dim3(512), dim3(256), 0, stream,
                       Wi_w, wihi, wilo);
    hipLaunchKernelGGL((xi_gemm_mfma_t<1>), dim3(512, 8), dim3(256), 0, stream,
                       x, Wi_w, Wi_b, out, wihi, wilo);
  } else {
    hipLaunchKernelGGL((xi_gemm_mfma_t<0>), dim3(512, 8), dim3(256), 0, stream,
                       x, Wi_w, Wi_b, out, wihi, wilo);
  }

  // Zero the barrier flags (graph replays reuse d_ws; flags must start 0)
  hipMemsetAsync(d_ws, 0, 4096, stream);

  // Phase 2: cooperative scan — R19 verbatim
  void* args[] = { (void*)&h0, (void*)&Wh_w, (void*)&Wh_b, (void*)&out,
                   (void*)&flags, (void*)&pk };
  hipLaunchCooperativeKernel((void*)rnn_scan, dim3(256), dim3(256), args, 0, stream);
}

// Round 22
// 3873.809 us; speedup vs baseline: 2.9109x; 1.1835x over previous
//
#include <hip/hip_runtime.h>
#include <cmath>

#define L_ 512
#define B_ 128
#define D_ 1024
#define H_ 1024
#define PKN (B_ * H_)  // one packed-h buffer: 128K ushorts = 256 KB

typedef __attribute__((ext_vector_type(8))) short bf16x8;
typedef __attribute__((ext_vector_type(4))) float f32x4;

static __device__ __forceinline__ unsigned short f32_bf16_rn(float f) {
  unsigned u = __float_as_uint(f);
  u += 0x7FFFu + ((u >> 16) & 1u);
  return (unsigned short)(u >> 16);
}
static __device__ __forceinline__ float bf16_f32(unsigned short h) {
  return __uint_as_float(((unsigned)h) << 16);
}

static __device__ __forceinline__ void pack8(const float4& u, const float4& v,
                                             bf16x8& hi, bf16x8& lo) {
  float f[8] = {u.x, u.y, u.z, u.w, v.x, v.y, v.z, v.w};
#pragma unroll
  for (int i = 0; i < 8; ++i) {
    const unsigned short h = f32_bf16_rn(f[i]);
    hi[i] = (short)h;
    lo[i] = (short)f32_bf16_rn(f[i] - bf16_f32(h));
  }
}

// ---------------------------------------------------------------------------
// pack_wi: one-time split of Wi (1024x1024 f32) into bf16 hi/lo arrays.
// ---------------------------------------------------------------------------
__global__ __launch_bounds__(256) void pack_wi(
    const float* __restrict__ W, unsigned short* __restrict__ hi,
    unsigned short* __restrict__ lo) {
  const size_t i = ((size_t)blockIdx.x * 256 + threadIdx.x) * 8;
  const float4 u = *(const float4*)&W[i];
  const float4 v = *(const float4*)&W[i + 4];
  bf16x8 h, l;
  pack8(u, v, h, l);
  *(bf16x8*)&hi[i] = h;
  *(bf16x8*)&lo[i] = l;
}

// ---------------------------------------------------------------------------
// Kernel A: xi = x @ Wi^T + bi, split-bf16 3-MFMA (R21: pre-packed Wi).
// ---------------------------------------------------------------------------
template <int PRE>
__global__ __launch_bounds__(256) void xi_gemm_mfma_t(
    const float* __restrict__ x, const float* __restrict__ Wi,
    const float* __restrict__ bi, float* __restrict__ out,
    const unsigned short* __restrict__ wihi,
    const unsigned short* __restrict__ wilo) {
  __shared__ unsigned short Ahi[128 * 32], Alo[128 * 32];
  __shared__ unsigned short Bhi[128 * 32], Blo[128 * 32];
  const int tid = threadIdx.x;
  const int bm = blockIdx.x, bn = blockIdx.y;
  const int lane = tid & 63, wv = tid >> 6;
  const int wm = wv >> 1, wn = wv & 1;

  const float* Ag = x + (size_t)bm * 128 * D_;
  const float* Bg = Wi + (size_t)bn * 128 * D_;

  f32x4 acc[4][4];
#pragma unroll
  for (int mi = 0; mi < 4; ++mi)
#pragma unroll
    for (int nj = 0; nj < 4; ++nj) acc[mi][nj] = (f32x4){0.f, 0.f, 0.f, 0.f};

  const int r = tid >> 1;
  const int h2 = tid & 1;
  const int sw = r & 3;
  const int s0 = (h2 * 2) ^ sw, s1 = (h2 * 2 + 1) ^ sw;
  const int fr = lane & 15, kg = lane >> 4;

  for (int k0 = 0; k0 < D_; k0 += 32) {
    __syncthreads();
    {
      const float* pa = &Ag[(size_t)r * D_ + k0 + h2 * 16];
      const float4 a0 = *(const float4*)(pa + 0), a1 = *(const float4*)(pa + 4);
      const float4 a2 = *(const float4*)(pa + 8), a3 = *(const float4*)(pa + 12);
      bf16x8 h, l;
      pack8(a0, a1, h, l);
      *(bf16x8*)&Ahi[r * 32 + s0 * 8] = h;
      *(bf16x8*)&Alo[r * 32 + s0 * 8] = l;
      pack8(a2, a3, h, l);
      *(bf16x8*)&Ahi[r * 32 + s1 * 8] = h;
      *(bf16x8*)&Alo[r * 32 + s1 * 8] = l;
      if constexpr (PRE) {
        const size_t wro = (size_t)(bn * 128 + r) * 1024 + k0 + h2 * 16;
        const unsigned short* ph = wihi + wro;
        const unsigned short* pl = wilo + wro;
        *(bf16x8*)&Bhi[r * 32 + s0 * 8] = *(const bf16x8*)(ph);
        *(bf16x8*)&Bhi[r * 32 + s1 * 8] = *(const bf16x8*)(ph + 8);
        *(bf16x8*)&Blo[r * 32 + s0 * 8] = *(const bf16x8*)(pl);
        *(bf16x8*)&Blo[r * 32 + s1 * 8] = *(const bf16x8*)(pl + 8);
      } else {
        const float* pb = &Bg[(size_t)r * D_ + k0 + h2 * 16];
        const float4 b0 = *(const float4*)(pb + 0), b1 = *(const float4*)(pb + 4);
        const float4 b2 = *(const float4*)(pb + 8), b3 = *(const float4*)(pb + 12);
        pack8(b0, b1, h, l);
        *(bf16x8*)&Bhi[r * 32 + s0 * 8] = h;
        *(bf16x8*)&Blo[r * 32 + s0 * 8] = l;
        pack8(b2, b3, h, l);
        *(bf16x8*)&Bhi[r * 32 + s1 * 8] = h;
        *(bf16x8*)&Blo[r * 32 + s1 * 8] = l;
      }
    }
    __syncthreads();

    bf16x8 Ah[4], Al[4], Bh[4], Bl[4];
#pragma unroll
    for (int mi = 0; mi < 4; ++mi) {
      const int row = wm * 64 + mi * 16 + fr;
      const int sl = kg ^ (row & 3);
      Ah[mi] = *(const bf16x8*)&Ahi[row * 32 + sl * 8];
      Al[mi] = *(const bf16x8*)&Alo[row * 32 + sl * 8];
    }
#pragma unroll
    for (int nj = 0; nj < 4; ++nj) {
      const int row = wn * 64 + nj * 16 + fr;
      const int sl = kg ^ (row & 3);
      Bh[nj] = *(const bf16x8*)&Bhi[row * 32 + sl * 8];
      Bl[nj] = *(const bf16x8*)&Blo[row * 32 + sl * 8];
    }
#pragma unroll
    for (int mi = 0; mi < 4; ++mi)
#pragma unroll
      for (int nj = 0; nj < 4; ++nj) {
        acc[mi][nj] = __builtin_amdgcn_mfma_f32_16x16x32_bf16(
            Ah[mi], Bh[nj], acc[mi][nj], 0, 0, 0);
        acc[mi][nj] = __builtin_amdgcn_mfma_f32_16x16x32_bf16(
            Ah[mi], Bl[nj], acc[mi][nj], 0, 0, 0);
        acc[mi][nj] = __builtin_amdgcn_mfma_f32_16x16x32_bf16(
            Al[mi], Bh[nj], acc[mi][nj], 0, 0, 0);
      }
  }

  const int fq = lane >> 4;
#pragma unroll
  for (int nj = 0; nj < 4; ++nj) {
    const int col = bn * 128 + wn * 64 + nj * 16 + fr;
    const float bias = bi[col];
#pragma unroll
    for (int mi = 0; mi < 4; ++mi)
#pragma unroll
      for (int reg = 0; reg < 4; ++reg) {
        const size_t row = (size_t)bm * 128 + wm * 64 + mi * 16 + fq * 4 + reg;
        out[row * H_ + col] = acc[mi][nj][reg] + bias;
      }
  }
}

// ---------------------------------------------------------------------------
// Kernel B v22 = R19/R21 scan with ONE change: SINGLE-BF16 h exchange.
//  * pk stores bf16(h) as ushort (was hi|lo u32): exchange bytes halve,
//    the 16B cached load per kt IS the MFMA B-operand (no v_perm unpack),
//    and the k-loop drops to 2 MFMA/kt (Ah x h_lo term vanishes).
//  * ACCURACY EXPERIMENT: injects ~6e-4/step (|Wh_hi x h_lo|); predicted
//    absmax 0.006-0.015 vs 0.02 threshold. If it fails, that measures the
//    exchange precision floor -> revert to R21.
//  * Sync skeleton/primitives FROZEN (R2-lineage + R18 fence placement).
// ---------------------------------------------------------------------------
__global__ __launch_bounds__(256, 1) void rnn_scan(
    const float* __restrict__ h0, const float* __restrict__ Wh,
    const float* __restrict__ bh, float* __restrict__ out,
    unsigned int* __restrict__ flags, unsigned short* __restrict__ pk16) {
  __shared__ unsigned short WhHi[32 * 1024];  // 64 KB
  __shared__ float red[2 * 32 * 17];          // 4.25 KB (stride-17)
  const int tid = threadIdx.x;
  const int g = blockIdx.x & 7;
  const int c = blockIdx.x >> 3;
  const int j0 = c << 5;
  const int b0 = g << 4;

  // ---- Stage Wh-hi rows j0..j0+31 into LDS (once) ----
#pragma unroll
  for (int i = 0; i < 16; ++i) {
    const int sid = i * 256 + tid;
    const int jr = sid >> 7;
    const int s = sid & 127;
    const float* p = &Wh[(size_t)(j0 + jr) * H_ + s * 8];
    const float4 u = *(const float4*)(p);
    const float4 v4 = *(const float4*)(p + 4);
    bf16x8 hi, lo;
    pack8(u, v4, hi, lo);
    *(bf16x8*)&WhHi[jr * 1024 + (s ^ (jr & 7)) * 8] = hi;
  }

  const int lane = tid & 63;
  const int wv = tid >> 6;
  const int jh = wv >> 1;          // j-half (0,1)
  const int kh = wv & 1;           // K-half (0,1)
  const int fr = lane & 15;
  const int kb = lane >> 4;
  const int frx7 = fr & 7;
  const int jrt = (jh * 16 + fr) * 1024;

  // ---- Wh-lo -> registers: 16 k-tiles x 8 bf16 per lane ----
  bf16x8 wlo[16];
  {
    const float* wrow = Wh + (size_t)(j0 + jh * 16 + fr) * H_ + kh * 512;
#pragma unroll
    for (int kt = 0; kt < 16; ++kt) {
      const float* p = wrow + kt * 32 + kb * 8;
      const float4 u = *(const float4*)(p);
      const float4 v4 = *(const float4*)(p + 4);
      bf16x8 hi;
      pack8(u, v4, hi, wlo[kt]);
    }
  }

  const int jf = tid & 31;
  const int bfh = tid >> 5;
  const float bias = bh[j0 + jf];
  unsigned int* gflags = flags + (g << 6);
  __syncthreads();

  const size_t hoffF = (size_t)fr * H_ + kh * 512;
  const size_t obase0 = (size_t)(b0 + bfh) * H_ + (j0 + jf);
  const size_t obase1 = obase0 + (size_t)8 * H_;
  float xi0 = out[obase0];
  float xi1 = out[obase1];
  for (int t = 0; t < L_; ++t) {
    const size_t tB = (size_t)t * B_ * H_;
    const size_t nB = tB + (size_t)(t + 1 < L_ ? B_ * H_ : 0);
    // xi[t+1] prefetch early (R17): completes under the k-loop; register
    // carry survives the acquire invalidate.
    const float xin0 = out[nB + obase0];
    const float xin1 = out[nB + obase1];

    f32x4 acc = (f32x4){0.f, 0.f, 0.f, 0.f};
    if (t == 0) {
      // f32 h0 (immutable input) -> bf16 hi, 2 MFMA chains
      const float* hb = h0 + (size_t)b0 * H_ + hoffF;
#pragma unroll
      for (int kt = 0; kt < 16; ++kt) {
        const float* hp = hb + kt * 32 + kb * 8;
        const float4 u = *(const float4*)(hp);
        const float4 v4 = *(const float4*)(hp + 4);
        bf16x8 Bh, Bl;
        pack8(u, v4, Bh, Bl);
        const int ps = (kh * 64 + kt * 4 + kb) ^ frx7;
        const bf16x8 Ah = *(const bf16x8*)&WhHi[jrt + ps * 8];
        acc = __builtin_amdgcn_mfma_f32_16x16x32_bf16(Ah, Bh, acc, 0, 0, 0);
        acc = __builtin_amdgcn_mfma_f32_16x16x32_bf16(wlo[kt], Bh, acc, 0, 0, 0);
      }
    } else {
      // single-bf16 path: one 16B cached load per kt IS the B-operand
      const bf16x8* pkb = (const bf16x8*)(
          pk16 + (size_t)((t + 1) & 1) * PKN + (size_t)b0 * H_ + hoffF +
          kb * 8);
#pragma unroll
      for (int kt = 0; kt < 16; ++kt) {
        const bf16x8 Bh = pkb[kt * 4];  // kt*32 ushorts = kt*4 bf16x8 units
        const int ps = (kh * 64 + kt * 4 + kb) ^ frx7;
        const bf16x8 Ah = *(const bf16x8*)&WhHi[jrt + ps * 8];
        acc = __builtin_amdgcn_mfma_f32_16x16x32_bf16(Ah, Bh, acc, 0, 0, 0);
        acc = __builtin_amdgcn_mfma_f32_16x16x32_bf16(wlo[kt], Bh, acc, 0, 0, 0);
      }
    }
#pragma unroll
    for (int r4 = 0; r4 < 4; ++r4)
      red[(kh * 32 + jh * 16 + kb * 4 + r4) * 17 + fr] = acc[r4];
    __syncthreads();
    {
      const float s0 = red[(jf) * 17 + bfh] + red[(32 + jf) * 17 + bfh];
      const float s1 = red[(jf) * 17 + bfh + 8] + red[(32 + jf) * 17 + bfh + 8];
      const float v0 = tanhf(s0 + xi0 + bias);
      const float v1 = tanhf(s1 + xi1 + bias);
      // out: sc1 write-through (R18 anchor)
      __hip_atomic_store(&out[tB + obase0], v0, __ATOMIC_RELAXED,
                         __HIP_MEMORY_SCOPE_AGENT);
      __hip_atomic_store(&out[tB + obase1], v1, __ATOMIC_RELAXED,
                         __HIP_MEMORY_SCOPE_AGENT);
      // pk: single bf16 per element, sc1 write-through
      unsigned short* pkw = pk16 + (size_t)(t & 1) * PKN;
      __hip_atomic_store(&pkw[obase0], f32_bf16_rn(v0), __ATOMIC_RELAXED,
                         __HIP_MEMORY_SCOPE_AGENT);
      __hip_atomic_store(&pkw[obase1], f32_bf16_rn(v1), __ATOMIC_RELAXED,
                         __HIP_MEMORY_SCOPE_AGENT);
    }

    if (t + 1 < L_) {
      // ---- release: drain, block done, publish (R13 verbatim) ----
      asm volatile("s_waitcnt vmcnt(0)" ::: "memory");
      __syncthreads();
      if (tid == 0)
        __hip_atomic_store(&gflags[c], (unsigned)(t + 1), __ATOMIC_RELAXED,
                           __HIP_MEMORY_SCOPE_AGENT);
      // ---- wave 0: poll the 32 group flags, then ONE acquire fence ----
      if (tid < 64) {
        const unsigned tgt = (unsigned)(t + 1);
        while (true) {
          const unsigned f = __hip_atomic_load(&gflags[tid & 31],
                                               __ATOMIC_RELAXED,
                                               __HIP_MEMORY_SCOPE_AGENT);
          if (__all((int)(f >= tgt))) break;
          __builtin_amdgcn_s_sleep(1);
        }
        __builtin_amdgcn_fence(__ATOMIC_ACQUIRE, "agent");
      }
      __syncthreads();
    }
    xi0 = xin0;
    xi1 = xin1;
  }
}

// ---------------------------------------------------------------------------
extern "C" void kernel_launch(void* const* d_in, const int* in_sizes, int n_in,
                              void* d_out, int out_size, void* d_ws, size_t ws_size,
                              hipStream_t stream) {
  const float* x    = (const float*)d_in[0];
  const float* h0   = (const float*)d_in[1];
  const float* Wi_w = (const float*)d_in[2];
  const float* Wi_b = (const float*)d_in[3];
  const float* Wh_w = (const float*)d_in[4];
  const float* Wh_b = (const float*)d_in[5];
  float* out = (float*)d_out;
  unsigned int* flags = (unsigned int*)d_ws;                    // 4 KB
  unsigned short* pk16 = (unsigned short*)((char*)d_ws + 4096); // 2 x 256 KB
  unsigned short* wihi =
      (unsigned short*)((char*)d_ws + 4096 + 2 * (size_t)PKN * 2);
  unsigned short* wilo = wihi + (size_t)H_ * D_;
  const size_t need = 4096 + 2 * (size_t)PKN * 2 + 2 * (size_t)H_ * D_ * 2;
  const bool pre = ws_size >= need;

  // Phase 1: xi -> d_out (split-bf16 MFMA; Wi pre-packed if ws allows)
  if (pre) {
    hipLaunchKernelGGL(pack_wi, dim3(512), dim3(256), 0, stream,
                       Wi_w, wihi, wilo);
    hipLaunchKernelGGL((xi_gemm_mfma_t<1>), dim3(512, 8), dim3(256), 0, stream,
                       x, Wi_w, Wi_b, out, wihi, wilo);
  } else {
    hipLaunchKernelGGL((xi_gemm_mfma_t<0>), dim3(512, 8), dim3(256), 0, stream,
                       x, Wi_w, Wi_b, out, wihi, wilo);
  }

  // Zero the barrier flags (graph replays reuse d_ws; flags must start 0)
  hipMemsetAsync(d_ws, 0, 4096, stream);

  // Phase 2: cooperative scan — single-bf16 exchange
  void* args[] = { (void*)&h0, (void*)&Wh_w, (void*)&Wh_b, (void*)&out,
                   (void*)&flags, (void*)&pk16 };
  hipLaunchCooperativeKernel((void*)rnn_scan, dim3(256), dim3(256), args, 0, stream);
}

// Round 23
// 3836.682 us; speedup vs baseline: 2.9390x; 1.0097x over previous
//
#include <hip/hip_runtime.h>
#include <cmath>

#define L_ 512
#define B_ 128
#define D_ 1024
#define H_ 1024
#define PKN (B_ * H_)  // one packed-h buffer: 128K ushorts = 256 KB

typedef __attribute__((ext_vector_type(8))) short bf16x8;
typedef __attribute__((ext_vector_type(4))) float f32x4;

static __device__ __forceinline__ unsigned short f32_bf16_rn(float f) {
  unsigned u = __float_as_uint(f);
  u += 0x7FFFu + ((u >> 16) & 1u);
  return (unsigned short)(u >> 16);
}
static __device__ __forceinline__ float bf16_f32(unsigned short h) {
  return __uint_as_float(((unsigned)h) << 16);
}

static __device__ __forceinline__ void pack8(const float4& u, const float4& v,
                                             bf16x8& hi, bf16x8& lo) {
  float f[8] = {u.x, u.y, u.z, u.w, v.x, v.y, v.z, v.w};
#pragma unroll
  for (int i = 0; i < 8; ++i) {
    const unsigned short h = f32_bf16_rn(f[i]);
    hi[i] = (short)h;
    lo[i] = (short)f32_bf16_rn(f[i] - bf16_f32(h));
  }
}

// hi-only pack (v23: A-lo term dropped in xi_gemm)
static __device__ __forceinline__ bf16x8 pack8hi(const float4& u,
                                                 const float4& v) {
  float f[8] = {u.x, u.y, u.z, u.w, v.x, v.y, v.z, v.w};
  bf16x8 hi;
#pragma unroll
  for (int i = 0; i < 8; ++i) hi[i] = (short)f32_bf16_rn(f[i]);
  return hi;
}

// ---------------------------------------------------------------------------
// pack_wi: one-time split of Wi (1024x1024 f32) into bf16 hi/lo arrays.
// ---------------------------------------------------------------------------
__global__ __launch_bounds__(256) void pack_wi(
    const float* __restrict__ W, unsigned short* __restrict__ hi,
    unsigned short* __restrict__ lo) {
  const size_t i = ((size_t)blockIdx.x * 256 + threadIdx.x) * 8;
  const float4 u = *(const float4*)&W[i];
  const float4 v = *(const float4*)&W[i + 4];
  bf16x8 h, l;
  pack8(u, v, h, l);
  *(bf16x8*)&hi[i] = h;
  *(bf16x8*)&lo[i] = l;
}

// ---------------------------------------------------------------------------
// Kernel A v23: xi = x @ Wi^T + bi, 2-MFMA split-bf16 (Ah*Bh + Ah*Bl).
// The Al*Bh (x_lo * Wi_hi) term is DROPPED: injects ~6e-4 std (max ~3e-3)
// into xi — within the verified error budget (R22 absmax 0.0049 vs 0.02).
// Saves 1/3 of MFMA work, the Alo LDS bank (32->24 KB), and A-lo pack VALU.
// ---------------------------------------------------------------------------
template <int PRE>
__global__ __launch_bounds__(256) void xi_gemm_mfma_t(
    const float* __restrict__ x, const float* __restrict__ Wi,
    const float* __restrict__ bi, float* __restrict__ out,
    const unsigned short* __restrict__ wihi,
    const unsigned short* __restrict__ wilo) {
  __shared__ unsigned short Ahi[128 * 32];
  __shared__ unsigned short Bhi[128 * 32], Blo[128 * 32];
  const int tid = threadIdx.x;
  const int bm = blockIdx.x, bn = blockIdx.y;
  const int lane = tid & 63, wv = tid >> 6;
  const int wm = wv >> 1, wn = wv & 1;

  const float* Ag = x + (size_t)bm * 128 * D_;
  const float* Bg = Wi + (size_t)bn * 128 * D_;

  f32x4 acc[4][4];
#pragma unroll
  for (int mi = 0; mi < 4; ++mi)
#pragma unroll
    for (int nj = 0; nj < 4; ++nj) acc[mi][nj] = (f32x4){0.f, 0.f, 0.f, 0.f};

  const int r = tid >> 1;
  const int h2 = tid & 1;
  const int sw = r & 3;
  const int s0 = (h2 * 2) ^ sw, s1 = (h2 * 2 + 1) ^ sw;
  const int fr = lane & 15, kg = lane >> 4;

  for (int k0 = 0; k0 < D_; k0 += 32) {
    __syncthreads();
    {
      const float* pa = &Ag[(size_t)r * D_ + k0 + h2 * 16];
      const float4 a0 = *(const float4*)(pa + 0), a1 = *(const float4*)(pa + 4);
      const float4 a2 = *(const float4*)(pa + 8), a3 = *(const float4*)(pa + 12);
      *(bf16x8*)&Ahi[r * 32 + s0 * 8] = pack8hi(a0, a1);
      *(bf16x8*)&Ahi[r * 32 + s1 * 8] = pack8hi(a2, a3);
      if constexpr (PRE) {
        const size_t wro = (size_t)(bn * 128 + r) * 1024 + k0 + h2 * 16;
        const unsigned short* ph = wihi + wro;
        const unsigned short* pl = wilo + wro;
        *(bf16x8*)&Bhi[r * 32 + s0 * 8] = *(const bf16x8*)(ph);
        *(bf16x8*)&Bhi[r * 32 + s1 * 8] = *(const bf16x8*)(ph + 8);
        *(bf16x8*)&Blo[r * 32 + s0 * 8] = *(const bf16x8*)(pl);
        *(bf16x8*)&Blo[r * 32 + s1 * 8] = *(const bf16x8*)(pl + 8);
      } else {
        const float* pb = &Bg[(size_t)r * D_ + k0 + h2 * 16];
        const float4 b0 = *(const float4*)(pb + 0), b1 = *(const float4*)(pb + 4);
        const float4 b2 = *(const float4*)(pb + 8), b3 = *(const float4*)(pb + 12);
        bf16x8 h, l;
        pack8(b0, b1, h, l);
        *(bf16x8*)&Bhi[r * 32 + s0 * 8] = h;
        *(bf16x8*)&Blo[r * 32 + s0 * 8] = l;
        pack8(b2, b3, h, l);
        *(bf16x8*)&Bhi[r * 32 + s1 * 8] = h;
        *(bf16x8*)&Blo[r * 32 + s1 * 8] = l;
      }
    }
    __syncthreads();

    bf16x8 Ah[4], Bh[4], Bl[4];
#pragma unroll
    for (int mi = 0; mi < 4; ++mi) {
      const int row = wm * 64 + mi * 16 + fr;
      const int sl = kg ^ (row & 3);
      Ah[mi] = *(const bf16x8*)&Ahi[row * 32 + sl * 8];
    }
#pragma unroll
    for (int nj = 0; nj < 4; ++nj) {
      const int row = wn * 64 + nj * 16 + fr;
      const int sl = kg ^ (row & 3);
      Bh[nj] = *(const bf16x8*)&Bhi[row * 32 + sl * 8];
      Bl[nj] = *(const bf16x8*)&Blo[row * 32 + sl * 8];
    }
#pragma unroll
    for (int mi = 0; mi < 4; ++mi)
#pragma unroll
      for (int nj = 0; nj < 4; ++nj) {
        acc[mi][nj] = __builtin_amdgcn_mfma_f32_16x16x32_bf16(
            Ah[mi], Bh[nj], acc[mi][nj], 0, 0, 0);
        acc[mi][nj] = __builtin_amdgcn_mfma_f32_16x16x32_bf16(
            Ah[mi], Bl[nj], acc[mi][nj], 0, 0, 0);
      }
  }

  const int fq = lane >> 4;
#pragma unroll
  for (int nj = 0; nj < 4; ++nj) {
    const int col = bn * 128 + wn * 64 + nj * 16 + fr;
    const float bias = bi[col];
#pragma unroll
    for (int mi = 0; mi < 4; ++mi)
#pragma unroll
      for (int reg = 0; reg < 4; ++reg) {
        const size_t row = (size_t)bm * 128 + wm * 64 + mi * 16 + fq * 4 + reg;
        out[row * H_ + col] = acc[mi][nj][reg] + bias;
      }
  }
}

// ---------------------------------------------------------------------------
// Kernel B: rnn_scan — VERBATIM R22 (3.29 ms, 6.4 us/step, proven).
// Sync semantics frozen: sc1 WT stores, vmcnt(0) drain, block barrier,
// tid0 sc1 flag, wave-0 agent poll, one agent acquire fence per block.
// ---------------------------------------------------------------------------
__global__ __launch_bounds__(256, 1) void rnn_scan(
    const float* __restrict__ h0, const float* __restrict__ Wh,
    const float* __restrict__ bh, float* __restrict__ out,
    unsigned int* __restrict__ flags, unsigned short* __restrict__ pk16) {
  __shared__ unsigned short WhHi[32 * 1024];  // 64 KB
  __shared__ float red[2 * 32 * 17];          // 4.25 KB (stride-17)
  const int tid = threadIdx.x;
  const int g = blockIdx.x & 7;
  const int c = blockIdx.x >> 3;
  const int j0 = c << 5;
  const int b0 = g << 4;

  // ---- Stage Wh-hi rows j0..j0+31 into LDS (once) ----
#pragma unroll
  for (int i = 0; i < 16; ++i) {
    const int sid = i * 256 + tid;
    const int jr = sid >> 7;
    const int s = sid & 127;
    const float* p = &Wh[(size_t)(j0 + jr) * H_ + s * 8];
    const float4 u = *(const float4*)(p);
    const float4 v4 = *(const float4*)(p + 4);
    bf16x8 hi, lo;
    pack8(u, v4, hi, lo);
    *(bf16x8*)&WhHi[jr * 1024 + (s ^ (jr & 7)) * 8] = hi;
  }

  const int lane = tid & 63;
  const int wv = tid >> 6;
  const int jh = wv >> 1;          // j-half (0,1)
  const int kh = wv & 1;           // K-half (0,1)
  const int fr = lane & 15;
  const int kb = lane >> 4;
  const int frx7 = fr & 7;
  const int jrt = (jh * 16 + fr) * 1024;

  // ---- Wh-lo -> registers: 16 k-tiles x 8 bf16 per lane ----
  bf16x8 wlo[16];
  {
    const float* wrow = Wh + (size_t)(j0 + jh * 16 + fr) * H_ + kh * 512;
#pragma unroll
    for (int kt = 0; kt < 16; ++kt) {
      const float* p = wrow + kt * 32 + kb * 8;
      const float4 u = *(const float4*)(p);
      const float4 v4 = *(const float4*)(p + 4);
      bf16x8 hi;
      pack8(u, v4, hi, wlo[kt]);
    }
  }

  const int jf = tid & 31;
  const int bfh = tid >> 5;
  const float bias = bh[j0 + jf];
  unsigned int* gflags = flags + (g << 6);
  __syncthreads();

  const size_t hoffF = (size_t)fr * H_ + kh * 512;
  const size_t obase0 = (size_t)(b0 + bfh) * H_ + (j0 + jf);
  const size_t obase1 = obase0 + (size_t)8 * H_;
  float xi0 = out[obase0];
  float xi1 = out[obase1];
  for (int t = 0; t < L_; ++t) {
    const size_t tB = (size_t)t * B_ * H_;
    const size_t nB = tB + (size_t)(t + 1 < L_ ? B_ * H_ : 0);
    // xi[t+1] prefetch early: completes under the k-loop; register carry
    // survives the acquire invalidate.
    const float xin0 = out[nB + obase0];
    const float xin1 = out[nB + obase1];

    f32x4 acc = (f32x4){0.f, 0.f, 0.f, 0.f};
    if (t == 0) {
      const float* hb = h0 + (size_t)b0 * H_ + hoffF;
#pragma unroll
      for (int kt = 0; kt < 16; ++kt) {
        const float* hp = hb + kt * 32 + kb * 8;
        const float4 u = *(const float4*)(hp);
        const float4 v4 = *(const float4*)(hp + 4);
        bf16x8 Bh, Bl;
        pack8(u, v4, Bh, Bl);
        const int ps = (kh * 64 + kt * 4 + kb) ^ frx7;
        const bf16x8 Ah = *(const bf16x8*)&WhHi[jrt + ps * 8];
        acc = __builtin_amdgcn_mfma_f32_16x16x32_bf16(Ah, Bh, acc, 0, 0, 0);
        acc = __builtin_amdgcn_mfma_f32_16x16x32_bf16(wlo[kt], Bh, acc, 0, 0, 0);
      }
    } else {
      // single-bf16 path: one 16B cached load per kt IS the B-operand
      const bf16x8* pkb = (const bf16x8*)(
          pk16 + (size_t)((t + 1) & 1) * PKN + (size_t)b0 * H_ + hoffF +
          kb * 8);
#pragma unroll
      for (int kt = 0; kt < 16; ++kt) {
        const bf16x8 Bh = pkb[kt * 4];
        const int ps = (kh * 64 + kt * 4 + kb) ^ frx7;
        const bf16x8 Ah = *(const bf16x8*)&WhHi[jrt + ps * 8];
        acc = __builtin_amdgcn_mfma_f32_16x16x32_bf16(Ah, Bh, acc, 0, 0, 0);
        acc = __builtin_amdgcn_mfma_f32_16x16x32_bf16(wlo[kt], Bh, acc, 0, 0, 0);
      }
    }
#pragma unroll
    for (int r4 = 0; r4 < 4; ++r4)
      red[(kh * 32 + jh * 16 + kb * 4 + r4) * 17 + fr] = acc[r4];
    __syncthreads();
    {
      const float s0 = red[(jf) * 17 + bfh] + red[(32 + jf) * 17 + bfh];
      const float s1 = red[(jf) * 17 + bfh + 8] + red[(32 + jf) * 17 + bfh + 8];
      const float v0 = tanhf(s0 + xi0 + bias);
      const float v1 = tanhf(s1 + xi1 + bias);
      __hip_atomic_store(&out[tB + obase0], v0, __ATOMIC_RELAXED,
                         __HIP_MEMORY_SCOPE_AGENT);
      __hip_atomic_store(&out[tB + obase1], v1, __ATOMIC_RELAXED,
                         __HIP_MEMORY_SCOPE_AGENT);
      unsigned short* pkw = pk16 + (size_t)(t & 1) * PKN;
      __hip_atomic_store(&pkw[obase0], f32_bf16_rn(v0), __ATOMIC_RELAXED,
                         __HIP_MEMORY_SCOPE_AGENT);
      __hip_atomic_store(&pkw[obase1], f32_bf16_rn(v1), __ATOMIC_RELAXED,
                         __HIP_MEMORY_SCOPE_AGENT);
    }

    if (t + 1 < L_) {
      // ---- release: drain, block done, publish ----
      asm volatile("s_waitcnt vmcnt(0)" ::: "memory");
      __syncthreads();
      if (tid == 0)
        __hip_atomic_store(&gflags[c], (unsigned)(t + 1), __ATOMIC_RELAXED,
                           __HIP_MEMORY_SCOPE_AGENT);
      // ---- wave 0: poll the 32 group flags, then ONE acquire fence ----
      if (tid < 64) {
        const unsigned tgt = (unsigned)(t + 1);
        while (true) {
          const unsigned f = __hip_atomic_load(&gflags[tid & 31],
                                               __ATOMIC_RELAXED,
                                               __HIP_MEMORY_SCOPE_AGENT);
          if (__all((int)(f >= tgt))) break;
          __builtin_amdgcn_s_sleep(1);
        }
        __builtin_amdgcn_fence(__ATOMIC_ACQUIRE, "agent");
      }
      __syncthreads();
    }
    xi0 = xin0;
    xi1 = xin1;
  }
}

// ---------------------------------------------------------------------------
extern "C" void kernel_launch(void* const* d_in, const int* in_sizes, int n_in,
                              void* d_out, int out_size, void* d_ws, size_t ws_size,
                              hipStream_t stream) {
  const float* x    = (const float*)d_in[0];
  const float* h0   = (const float*)d_in[1];
  const float* Wi_w = (const float*)d_in[2];
  const float* Wi_b = (const float*)d_in[3];
  const float* Wh_w = (const float*)d_in[4];
  const float* Wh_b = (const float*)d_in[5];
  float* out = (float*)d_out;
  unsigned int* flags = (unsigned int*)d_ws;                    // 4 KB
  unsigned short* pk16 = (unsigned short*)((char*)d_ws + 4096); // 2 x 256 KB
  unsigned short* wihi =
      (unsigned short*)((char*)d_ws + 4096 + 2 * (size_t)PKN * 2);
  unsigned short* wilo = wihi + (size_t)H_ * D_;
  const size_t need = 4096 + 2 * (size_t)PKN * 2 + 2 * (size_t)H_ * D_ * 2;
  const bool pre = ws_size >= need;

  // Phase 1: xi -> d_out (2-MFMA split-bf16; Wi pre-packed if ws allows)
  if (pre) {
    hipLaunchKernelGGL(pack_wi, dim3(512), dim3(256), 0, stream,
                       Wi_w, wihi, wilo);
    hipLaunchKernelGGL((xi_gemm_mfma_t<1>), dim3(512, 8), dim3(256), 0, stream,
                       x, Wi_w, Wi_b, out, wihi, wilo);
  } else {
    hipLaunchKernelGGL((xi_gemm_mfma_t<0>), dim3(512, 8), dim3(256), 0, stream,
                       x, Wi_w, Wi_b, out, wihi, wilo);
  }

  // Zero the barrier flags (graph replays reuse d_ws; flags must start 0)
  hipMemsetAsync(d_ws, 0, 4096, stream);

  // Phase 2: cooperative scan — R22 verbatim (single-bf16 exchange)
  void* args[] = { (void*)&h0, (void*)&Wh_w, (void*)&Wh_b, (void*)&out,
                   (void*)&flags, (void*)&pk16 };
  hipLaunchCooperativeKernel((void*)rnn_scan, dim3(256), dim3(256), args, 0, stream);
}